// Round 6
// baseline (296.321 us; speedup 1.0000x reference)
//
#include <hip/hip_runtime.h>
#include <hip/hip_bf16.h>
#include <stdint.h>

#define BATCH 4
#define SEQ   4096          // 64*64 spatial
#define CH    512
#define NGRP  32
#define GEPS  1e-6f

typedef short  short8  __attribute__((ext_vector_type(8)));
typedef float  floatx4 __attribute__((ext_vector_type(4)));
typedef long   longx2  __attribute__((ext_vector_type(2)));

static __device__ __forceinline__ short bf16b(float f) {
    __hip_bfloat16 h = __float2bfloat16(f);
    return __builtin_bit_cast(short, h);
}
static __device__ __forceinline__ float bf2f(short s) {
    unsigned u = ((unsigned)(unsigned short)s) << 16;
    return __builtin_bit_cast(float, u);
}
static __device__ __forceinline__ char fp8b(float f) {
    int pk = __builtin_amdgcn_cvt_pk_fp8_f32(f, f, 0, false);
    return (char)(pk & 0xff);
}

// async global->LDS, 16B per lane. LDS dest = wave-uniform base + lane*16.
static __device__ __forceinline__ void dma16(const void* g, void* l) {
    __builtin_amdgcn_global_load_lds(
        (const __attribute__((address_space(1))) unsigned int*)g,
        (__attribute__((address_space(3))) unsigned int*)l, 16, 0, 0);
}

// max-reduce across the 16 lanes of a DPP row, pure VALU
static __device__ __forceinline__ float rowmax16(float x) {
    int xi = __builtin_bit_cast(int, x);
    x = fmaxf(x, __builtin_bit_cast(float, __builtin_amdgcn_update_dpp(xi, xi, 0x128, 0xf, 0xf, true))); // row_ror:8
    xi = __builtin_bit_cast(int, x);
    x = fmaxf(x, __builtin_bit_cast(float, __builtin_amdgcn_update_dpp(xi, xi, 0x124, 0xf, 0xf, true))); // row_ror:4
    xi = __builtin_bit_cast(int, x);
    x = fmaxf(x, __builtin_bit_cast(float, __builtin_amdgcn_update_dpp(xi, xi, 0x122, 0xf, 0xf, true))); // row_ror:2
    xi = __builtin_bit_cast(int, x);
    x = fmaxf(x, __builtin_bit_cast(float, __builtin_amdgcn_update_dpp(xi, xi, 0x121, 0xf, 0xf, true))); // row_ror:1
    return x;
}

// ---------------- GroupNorm partial sums ----------------
__global__ __launch_bounds__(256) void gn_partial_kernel(const float* __restrict__ x,
                                                         float* __restrict__ statsraw) {
    int blk = blockIdx.x;                 // 0..255
    int t = threadIdx.x;
    size_t row0 = (size_t)blk * 64;
    int qd = t & 127;
    int rh = t >> 7;
    const float* base = x + row0 * 512 + qd * 4;
    float s1 = 0.f, s2 = 0.f;
    #pragma unroll 4
    for (int i = 0; i < 32; ++i) {
        int r = rh + i * 2;
        float4 v = *reinterpret_cast<const float4*>(base + (size_t)r * 512);
        s1 += v.x + v.y + v.z + v.w;
        s2 += v.x * v.x + v.y * v.y + v.z * v.z + v.w * v.w;
    }
    __shared__ float a1[256], a2[256];
    a1[t] = s1; a2[t] = s2;
    __syncthreads();
    if (t < 32) {
        float u1 = 0.f, u2 = 0.f;
        #pragma unroll
        for (int e = 0; e < 4; ++e) {
            u1 += a1[t * 4 + e] + a1[128 + t * 4 + e];
            u2 += a2[t * 4 + e] + a2[128 + t * 4 + e];
        }
        int b = (int)(row0 >> 12);
        atomicAdd(&statsraw[(b * 32 + t) * 2],     u1);
        atomicAdd(&statsraw[(b * 32 + t) * 2 + 1], u2);
    }
}

// ---------------- GroupNorm apply ----------------
__global__ __launch_bounds__(256) void gn_apply_kernel(const float* __restrict__ x,
                                                       const float* __restrict__ statsraw,
                                                       const float* __restrict__ gsc,
                                                       const float* __restrict__ gbs,
                                                       short* __restrict__ xn) {
    int i4 = blockIdx.x * 256 + threadIdx.x;
    int base = i4 * 4;
    int b = base >> 21;
    int c = base & 511;
    int sidx = (b * 32 + (c >> 4)) * 2;
    float s1 = statsraw[sidx], s2 = statsraw[sidx + 1];
    float mean = s1 * (1.f / 65536.f);
    float var  = s2 * (1.f / 65536.f) - mean * mean;
    float rstd = rsqrtf(var + GEPS);
    float4 xv = reinterpret_cast<const float4*>(x)[i4];
    float4 sv = *reinterpret_cast<const float4*>(gsc + c);
    float4 bv = *reinterpret_cast<const float4*>(gbs + c);
    union { short s[4]; uint2 u; } p;
    p.s[0] = bf16b((xv.x - mean) * rstd * sv.x + bv.x);
    p.s[1] = bf16b((xv.y - mean) * rstd * sv.y + bv.y);
    p.s[2] = bf16b((xv.z - mean) * rstd * sv.z + bv.z);
    p.s[3] = bf16b((xv.w - mean) * rstd * sv.w + bv.w);
    reinterpret_cast<uint2*>(xn)[i4] = p.u;
}

// ---------------- weight transpose ----------------
__global__ __launch_bounds__(256) void wtrans_kernel(const float* __restrict__ w0,
                                                     const float* __restrict__ w1,
                                                     const float* __restrict__ w2,
                                                     const float* __restrict__ w3,
                                                     short* __restrict__ wT) {
    const float* w = (blockIdx.z == 0) ? w0 : (blockIdx.z == 1) ? w1
                   : (blockIdx.z == 2) ? w2 : w3;
    short* out = wT + (size_t)blockIdx.z * CH * CH;
    int n0 = blockIdx.x * 32, k0 = blockIdx.y * 32;
    int tx = threadIdx.x, ty = threadIdx.y;
    __shared__ float s[32][33];
    #pragma unroll
    for (int i = 0; i < 4; ++i) {
        int kk = ty + i * 8;
        s[kk][tx] = w[(size_t)(k0 + kk) * CH + n0 + tx];
    }
    __syncthreads();
    #pragma unroll
    for (int i = 0; i < 4; ++i) {
        int nn = ty + i * 8;
        out[(size_t)(n0 + nn) * CH + k0 + tx] = bf16b(s[tx][nn]);
    }
}

// ---------------- fused QKV GEMM: fp8 epilogue ------------------------------------
// q8 row-major.
// k8 pair-interleaved tile layout (16KB per 32-row s-block), for flash's paired
//   b128 K reads: byte(b,s,d) = b*2M + (s>>5)*16384 + (s&15)*1024
//                               + (d>>3)*16 + ((s>>4)&1)*8 + (d&7)
//   -> a 16B slot holds chunk d/8 of rows s and s+16.
// vT8 s-col-interleaved (P order) AND pair-interleaved tile layout
//   (16KB per 32-s block): byte(b,d,si) = b*2M + (si>>5)*16384
//     + (((d>>5)*16 + (d&15))*4 + ((si&31)>>3))*16 + ((d>>4)&1)*8 + (si&7)
//   -> a 16B slot holds s-chunk m of rows d and d+16.
__global__ __launch_bounds__(256) void gemm_qkv_kernel(const short* __restrict__ A,
                                                       const short* __restrict__ wT,
                                                       const float* __restrict__ bq,
                                                       const float* __restrict__ bk,
                                                       const float* __restrict__ bv,
                                                       char* __restrict__ q8,
                                                       char* __restrict__ k8,
                                                       char* __restrict__ vT8) {
    __shared__ short As[128 * 64];
    __shared__ short Bs[128 * 64];
    __shared__ char  vls[128 * 144];   // fp8 transpose staging, pitch 144
    int m0 = blockIdx.x * 128;
    int nblk = blockIdx.y;                  // 0..11
    int which = nblk >> 2;                  // 0=q,1=k,2=v (block-uniform)
    int n0 = (nblk & 3) * 128;
    const short* BT = wT + (size_t)which * 512 * 512;
    const float* bias = (which == 0) ? bq : (which == 1) ? bk : bv;
    int t = threadIdx.x;
    int w = t >> 6, lane = t & 63;
    int wr = w >> 1, wc = w & 1;
    int l15 = lane & 15, l4 = lane >> 4;
    floatx4 acc[4][4];
    #pragma unroll
    for (int i = 0; i < 4; ++i)
        #pragma unroll
        for (int j = 0; j < 4; ++j) acc[i][j] = (floatx4){0.f, 0.f, 0.f, 0.f};

    for (int k0 = 0; k0 < 512; k0 += 64) {
        __syncthreads();
        #pragma unroll
        for (int i = 0; i < 4; ++i) {
            int c = i * 256 + t;
            int row = c >> 3, j = (c & 7) ^ (row & 7);
            dma16(&A[(size_t)(m0 + row) * 512 + k0 + j * 8], &As[(c & ~63) * 8]);
            dma16(&BT[(size_t)(n0 + row) * 512 + k0 + j * 8], &Bs[(c & ~63) * 8]);
        }
        __syncthreads();
        #pragma unroll
        for (int kk = 0; kk < 64; kk += 32) {
            short8 af[4], bf[4];
            #pragma unroll
            for (int i = 0; i < 4; ++i) {
                int row = wr * 64 + i * 16 + l15;
                int j = (kk >> 3) + l4;
                af[i] = *reinterpret_cast<const short8*>(&As[(row * 8 + (j ^ (l15 & 7))) * 8]);
            }
            #pragma unroll
            for (int j2 = 0; j2 < 4; ++j2) {
                int row = wc * 64 + j2 * 16 + l15;
                int j = (kk >> 3) + l4;
                bf[j2] = *reinterpret_cast<const short8*>(&Bs[(row * 8 + (j ^ (l15 & 7))) * 8]);
            }
            #pragma unroll
            for (int i = 0; i < 4; ++i)
                #pragma unroll
                for (int j2 = 0; j2 < 4; ++j2)
                    acc[i][j2] = __builtin_amdgcn_mfma_f32_16x16x32_bf16(af[i], bf[j2], acc[i][j2], 0, 0, 0);
        }
    }
    if (which == 0) {
        #pragma unroll
        for (int i = 0; i < 4; ++i)
            #pragma unroll
            for (int j = 0; j < 4; ++j)
                #pragma unroll
                for (int r = 0; r < 4; ++r) {
                    int row = m0 + wr * 64 + i * 16 + l4 * 4 + r;
                    int col = n0 + wc * 64 + j * 16 + l15;
                    q8[(size_t)row * 512 + col] = fp8b(acc[i][j][r] + bias[col]);
                }
    } else if (which == 1) {
        // k8: pair-interleaved tile layout (see header comment)
        #pragma unroll
        for (int i = 0; i < 4; ++i)
            #pragma unroll
            for (int j = 0; j < 4; ++j)
                #pragma unroll
                for (int r = 0; r < 4; ++r) {
                    int row = m0 + wr * 64 + i * 16 + l4 * 4 + r;
                    int col = n0 + wc * 64 + j * 16 + l15;
                    int bb = row >> 12, s = row & 4095;
                    size_t idx = (size_t)bb * 2097152 + (size_t)(s >> 5) * 16384
                               + (s & 15) * 1024 + ((s >> 4) & 1) * 8
                               + (col >> 3) * 16 + (col & 7);
                    k8[idx] = fp8b(acc[i][j][r] + bias[col]);
                }
    } else {
        // v: transpose via LDS, with s-columns pair-interleaved per 32-block
        __syncthreads();
        #pragma unroll
        for (int i = 0; i < 4; ++i)
            #pragma unroll
            for (int j = 0; j < 4; ++j)
                #pragma unroll
                for (int r = 0; r < 4; ++r) {
                    int rl = wr * 64 + i * 16 + l4 * 4 + r;     // local row (sequence)
                    int rp = (rl & ~31) | (((rl & 15) << 1) | ((rl >> 4) & 1));  // interleave
                    int cl = wc * 64 + j * 16 + l15;            // local col (d)
                    vls[cl * 144 + rp] = fp8b(acc[i][j][r] + bias[n0 + cl]);
                }
        __syncthreads();
        int b = m0 >> 12, l0 = m0 & 4095;
        #pragma unroll
        for (int p = 0; p < 4; ++p) {
            int slot = p * 256 + t;
            int c = slot >> 3, off = (slot & 7) * 16;   // off multiple of 16
            uint4 v;
            __builtin_memcpy(&v, &vls[c * 144 + off], 16);
            int dcol = n0 + c;
            int g = dcol >> 5, rr = dcol & 15, h = (dcol >> 4) & 1;
            int s = l0 + off;                    // interleaved s index, mult of 16
            int sb = s >> 5, mb = (s & 31) >> 3; // mb = 0 or 2
            char* dst = vT8 + (size_t)b * 2097152 + (size_t)sb * 16384
                      + (size_t)((((g * 16 + rr) * 4 + mb) * 16) + h * 8);
            unsigned long long lo = ((unsigned long long)v.y << 32) | v.x;
            unsigned long long hi = ((unsigned long long)v.w << 32) | v.z;
            *reinterpret_cast<unsigned long long*>(dst)      = lo;  // chunk mb
            *reinterpret_cast<unsigned long long*>(dst + 16) = hi;  // chunk mb+1
        }
    }
}

// ---------------- output GEMM with FUSED combine: A = merge(Opart0, Opart1, ml) ------
// NOTE: ml max values are in BASE-2 units (flash computes softmax with exp2),
// so the merge uses exp2f.
__global__ __launch_bounds__(256) void gemm_bt_kernel(const short* __restrict__ Opart,
                                                      const float* __restrict__ ml,
                                                      const short* __restrict__ BT,
                                                      const float* __restrict__ bias,
                                                      float* __restrict__ outf,
                                                      const float* __restrict__ resid) {
    __shared__ short As[128 * 64];
    __shared__ short Bs[128 * 64];
    int m0 = blockIdx.x * 128, n0 = blockIdx.y * 128;
    int t = threadIdx.x;
    int w = t >> 6, lane = t & 63;
    int wr = w >> 1, wc = w & 1;
    int l15 = lane & 15, l4 = lane >> 4;
    const size_t PART = (size_t)BATCH * SEQ;   // 16384 rows per part
    floatx4 acc[4][4];
    #pragma unroll
    for (int i = 0; i < 4; ++i)
        #pragma unroll
        for (int j = 0; j < 4; ++j) acc[i][j] = (floatx4){0.f, 0.f, 0.f, 0.f};

    for (int k0 = 0; k0 < 512; k0 += 64) {
        __syncthreads();
        #pragma unroll
        for (int i = 0; i < 4; ++i) {
            int c = i * 256 + t;
            int rl = c >> 3, j = (c & 7) ^ (rl & 7);
            size_t rowg = (size_t)(m0 + rl);
            const short* s0 = Opart + rowg * 512 + k0 + j * 8;
            const short* s1 = s0 + PART * 512;
            uint4 a0 = *reinterpret_cast<const uint4*>(s0);
            uint4 a1 = *reinterpret_cast<const uint4*>(s1);
            float mA = ml[rowg * 2],          lA = ml[rowg * 2 + 1];
            float mB = ml[(PART + rowg) * 2], lB = ml[(PART + rowg) * 2 + 1];
            float mm = fmaxf(mA, mB);
            float e0 = exp2f(mA - mm), e1 = exp2f(mB - mm);
            float inv = 1.f / (e0 * lA + e1 * lB);
            e0 *= inv; e1 *= inv;
            union { uint4 u; short s[8]; } ua, ub, uo;
            ua.u = a0; ub.u = a1;
            #pragma unroll
            for (int e = 0; e < 8; ++e)
                uo.s[e] = bf16b(bf2f(ua.s[e]) * e0 + bf2f(ub.s[e]) * e1);
            *reinterpret_cast<uint4*>(&As[c * 8]) = uo.u;    // ds_write_b128
            dma16(&BT[(size_t)(n0 + rl) * 512 + k0 + j * 8], &Bs[(c & ~63) * 8]);
        }
        __syncthreads();
        #pragma unroll
        for (int kk = 0; kk < 64; kk += 32) {
            short8 af[4], bf[4];
            #pragma unroll
            for (int i = 0; i < 4; ++i) {
                int row = wr * 64 + i * 16 + l15;
                int j = (kk >> 3) + l4;
                af[i] = *reinterpret_cast<const short8*>(&As[(row * 8 + (j ^ (l15 & 7))) * 8]);
            }
            #pragma unroll
            for (int j2 = 0; j2 < 4; ++j2) {
                int row = wc * 64 + j2 * 16 + l15;
                int j = (kk >> 3) + l4;
                bf[j2] = *reinterpret_cast<const short8*>(&Bs[(row * 8 + (j ^ (l15 & 7))) * 8]);
            }
            #pragma unroll
            for (int i = 0; i < 4; ++i)
                #pragma unroll
                for (int j2 = 0; j2 < 4; ++j2)
                    acc[i][j2] = __builtin_amdgcn_mfma_f32_16x16x32_bf16(af[i], bf[j2], acc[i][j2], 0, 0, 0);
        }
    }
    #pragma unroll
    for (int i = 0; i < 4; ++i)
        #pragma unroll
        for (int j = 0; j < 4; ++j)
            #pragma unroll
            for (int r = 0; r < 4; ++r) {
                int row = m0 + wr * 64 + i * 16 + l4 * 4 + r;
                int col = n0 + wc * 64 + j * 16 + l15;
                float vv = acc[i][j][r] + bias[col];
                outf[(size_t)row * 512 + col] = vv + resid[(size_t)row * 512 + col];
            }
}

// ---------------- flash attention: fp8, transposed-PV work split --------------------
// LDS-traffic fix: all 4 waves used to read the SAME 16KB V tile (4x redundancy).
// Now wave w computes O[all 64 q][d-slice w*128..w*128+128):
//   phase 1 (pre bar A): QK^T for own 16q chunk (unchanged), softmax, P/al/flag
//     writes, lacc MFMA from own P (same-wave read, memcpy-ordered).
//   bar A: P + al + flags visible; K[cur] reads done; DMA(it+1) drained here.
//   phase 2: read 4 P chunks (4x ds_read_b64) + own 4KB V slice (4x b128, reused
//     across chunks); apply cross-wave rescale al (only when block flag set);
//     32 PV MFMAs into acc[c*8+dt] = O[c*16+l4*4+r][w*128+dt*16+l15].
//   bar B: V[cur]/P reads done before next iter overwrites.
// Per-wave LDS/iter: 16KB K + 4KB V + 2.5KB P vs 32.5KB before -> LDS pipe
// ~2250 cy/CU-iter, below MFMA's ~2550 -> MFMA-bound.
// Barrier ledger: K[cur] read pre-barA, overwritten by stage(it+2) post-barB(it). OK
//   V[cur] read in [barA,barB](it); overwritten post-barB(it+1).               OK
//   P/al/flg written pre-barA, read [barA,barB], rewritten pre-barA(it+1)
//     which is post-barB(it).                                                  OK
__global__ __launch_bounds__(256, 2) void flash_kernel(const char* __restrict__ q8,
                                                       const char* __restrict__ k8,
                                                       const char* __restrict__ v8,
                                                       short* __restrict__ Opart,
                                                       float* __restrict__ ml) {
    // K dbuf 32K | V dbuf 32K | P 2560 | al 256 | flags 16
    __shared__ __align__(16) char smem[68368];
    int bx = blockIdx.x;                 // 0..511
    int pb = bx & 7;                     // XCD-local (part,b)
    int part = pb >> 2, b = pb & 3;
    int q0 = (bx >> 3) * 64;
    int t = threadIdx.x, w = t >> 6, lane = t & 63;
    int l15 = lane & 15, l4 = lane >> 4;
    const float c2 = 0.06375873735f;     // (1/sqrt(512)) * log2(e)
    const float MARGIN = 7.2134752f;     // 5*log2(e); p <= 2^7.21 = 148 < 448

    // Q fp8 fragments: rows w*16 + l15, all 512 k (8 B per ks-step)
    long qf[16];
    {
        const char* qrow = q8 + ((size_t)b * SEQ + q0 + w * 16 + l15) * 512;
        #pragma unroll
        for (int ks = 0; ks < 16; ++ks)
            qf[ks] = *reinterpret_cast<const long*>(qrow + ks * 32 + l4 * 8);
    }

    // acc[c*8+dt][r] = O[q0 + c*16 + l4*4 + r][w*128 + dt*16 + l15]
    floatx4 acc[32];
    #pragma unroll
    for (int i = 0; i < 32; ++i) acc[i] = (floatx4){0.f, 0.f, 0.f, 0.f};
    floatx4 lacc = (floatx4){0.f, 0.f, 0.f, 0.f};
    float mused[4] = {-1e30f, -1e30f, -1e30f, -1e30f};

    const long ones = 0x3838383838383838L;   // e4m3 1.0 x8

    const char* kbase = k8 + (size_t)b * SEQ * 512;
    const char* vbase = v8 + (size_t)b * 512 * SEQ;
    const int sb0 = part * 64;           // first 32-s block of this part

    const int ksw = l15 & 7;
    const int vsw = (l15 >> 1) & 3;
    // loop-invariant LDS read bases; per-iter offset = cur*16384 (+ immediates)
    const char* kA_E = smem + ((l15 * 64 + (l4 ^ ksw)) << 4);
    const char* kA_O = smem + ((l15 * 64 + ((4 + l4) ^ ksw)) << 4);
    // own 128-d slice: g = w*4 + k  ->  base + w*4096 + k*1024
    const char* vA   = smem + 32768 + w * 4096 + ((l15 * 4 + (l4 ^ vsw)) << 4);
    char* Ps  = smem + 65536 + w * 640;   // own P chunk (pitch-40 rows)
    char* Pb  = smem + 65536;             // all P chunks
    char* alB = smem + 68096;             // 4 waves x 16 floats
    int*  flg = (int*)(smem + 68352);     // 4 ints

    // precomputed per-thread DMA source byte-offsets (swizzle folded in)
    int kSrc[4], vSrc[4];
    #pragma unroll
    for (int i = 0; i < 4; ++i) {
        int c = i * 256 + t;
        kSrc[i] = (((c & ~63) | ((c & 63) ^ ((c >> 6) & 7))) << 4);
        vSrc[i] = (((c & ~3)  | ((c & 3)  ^ ((c >> 3) & 3))) << 4);
    }
    const int ldsD = (t & ~63) << 4;   // wave-uniform: w*1024

    auto stage = [&](int sb, int buf) {
        const char* kt = kbase + (size_t)sb * 16384;
        const char* vt = vbase + (size_t)sb * 16384;
        char* Kd = smem + buf * 16384 + ldsD;
        char* Vd = smem + 32768 + buf * 16384 + ldsD;
        #pragma unroll
        for (int i = 0; i < 4; ++i) dma16(kt + kSrc[i], Kd + i * 4096);
        #pragma unroll
        for (int i = 0; i < 4; ++i) dma16(vt + vSrc[i], Vd + i * 4096);
    };

    stage(sb0, 0);
    __syncthreads();                                   // tile 0 ready

    for (int it = 0; it < 64; ++it) {
        int cur = it & 1;
        int coff = cur << 14;
        if (it + 1 < 64) stage(sb0 + it + 1, 1 - cur);

        // --- QK^T (fp8) for own 16q chunk: one b128 per K-row pair
        floatx4 sa0 = (floatx4){0.f, 0.f, 0.f, 0.f};
        floatx4 sa1 = (floatx4){0.f, 0.f, 0.f, 0.f};
        #pragma unroll
        for (int j = 0; j < 8; ++j) {
            longx2 kE = *reinterpret_cast<const longx2*>(kA_E + coff + j * 128);
            longx2 kO = *reinterpret_cast<const longx2*>(kA_O + coff + j * 128);
            sa0 = __builtin_amdgcn_mfma_f32_16x16x32_fp8_fp8(qf[2 * j],     kE[0], sa0, 0, 0, 0);
            sa1 = __builtin_amdgcn_mfma_f32_16x16x32_fp8_fp8(qf[2 * j],     kE[1], sa1, 0, 0, 0);
            sa0 = __builtin_amdgcn_mfma_f32_16x16x32_fp8_fp8(qf[2 * j + 1], kO[0], sa0, 0, 0, 0);
            sa1 = __builtin_amdgcn_mfma_f32_16x16x32_fp8_fp8(qf[2 * j + 1], kO[1], sa1, 0, 0, 0);
        }

        // --- online softmax, base-2, lazy rescale (own 16 rows)
        float v0[4], v1[4], nm4[4];
        bool need = false;
        #pragma unroll
        for (int r = 0; r < 4; ++r) {
            v0[r] = sa0[r] * c2; v1[r] = sa1[r] * c2;
            nm4[r] = rowmax16(fmaxf(v0[r], v1[r]));
            need |= (nm4[r] > mused[r] + MARGIN);
        }
        floatx4 alv = (floatx4){1.f, 1.f, 1.f, 1.f};
        int myf = (__ballot(need) != 0ull) ? 1 : 0;
        if (myf) {
            #pragma unroll
            for (int r = 0; r < 4; ++r) {
                float nm = fmaxf(mused[r], nm4[r]);
                float al = exp2f(mused[r] - nm);
                lacc[r] *= al;
                mused[r] = nm;
                alv[r] = al;
            }
        }
        if (l15 == 0) *reinterpret_cast<floatx4*>(alB + w * 64 + l4 * 16) = alv;
        if (lane == 0) flg[w] = myf;
        // P (fp8) write: interleaved col pairs (c, c+16) -> mem cols (2c, 2c+1)
        #pragma unroll
        for (int r = 0; r < 4; ++r) {
            int pk = __builtin_amdgcn_cvt_pk_fp8_f32(exp2f(v0[r] - mused[r]),
                                                     exp2f(v1[r] - mused[r]), 0, false);
            *reinterpret_cast<short*>(Ps + (l4 * 4 + r) * 40 + l15 * 2) = (short)pk;
        }
        // lacc from own P (same-wave read; memcpy = may-alias pun, ordered
        // after the short stores). Must follow the lacc rescale above.
        {
            long pfOwn;
            __builtin_memcpy(&pfOwn, (const char*)__builtin_assume_aligned(Ps + l15 * 40 + l4 * 8, 8), 8);
            lacc = __builtin_amdgcn_mfma_f32_16x16x32_fp8_fp8(pfOwn, ones, lacc, 0, 0, 0);
        }

        __syncthreads();   // bar A: P/al/flg visible; K[cur] reads done; DMA drained

        // --- phase 2: PV over own d-slice for ALL 64 q rows
        int anyf = flg[0] | flg[1] | flg[2] | flg[3];
        long pfA[4];
        #pragma unroll
        for (int c = 0; c < 4; ++c)
            __builtin_memcpy(&pfA[c], (const char*)__builtin_assume_aligned(
                                 Pb + c * 640 + l15 * 40 + l4 * 8, 8), 8);
        longx2 vv0 = *reinterpret_cast<const longx2*>(vA + coff);
        longx2 vv1 = *reinterpret_cast<const longx2*>(vA + coff + 1024);
        longx2 vv2 = *reinterpret_cast<const longx2*>(vA + coff + 2048);
        longx2 vv3 = *reinterpret_cast<const longx2*>(vA + coff + 3072);
        if (anyf) {
            #pragma unroll
            for (int c = 0; c < 4; ++c) {
                floatx4 a = *reinterpret_cast<const floatx4*>(alB + c * 64 + l4 * 16);
                #pragma unroll
                for (int dt = 0; dt < 8; ++dt) acc[c * 8 + dt] *= a;
            }
        }
        #pragma unroll
        for (int c = 0; c < 4; ++c) {
            acc[c*8+0] = __builtin_amdgcn_mfma_f32_16x16x32_fp8_fp8(pfA[c], vv0[0], acc[c*8+0], 0, 0, 0);
            acc[c*8+1] = __builtin_amdgcn_mfma_f32_16x16x32_fp8_fp8(pfA[c], vv0[1], acc[c*8+1], 0, 0, 0);
            acc[c*8+2] = __builtin_amdgcn_mfma_f32_16x16x32_fp8_fp8(pfA[c], vv1[0], acc[c*8+2], 0, 0, 0);
            acc[c*8+3] = __builtin_amdgcn_mfma_f32_16x16x32_fp8_fp8(pfA[c], vv1[1], acc[c*8+3], 0, 0, 0);
            acc[c*8+4] = __builtin_amdgcn_mfma_f32_16x16x32_fp8_fp8(pfA[c], vv2[0], acc[c*8+4], 0, 0, 0);
            acc[c*8+5] = __builtin_amdgcn_mfma_f32_16x16x32_fp8_fp8(pfA[c], vv2[1], acc[c*8+5], 0, 0, 0);
            acc[c*8+6] = __builtin_amdgcn_mfma_f32_16x16x32_fp8_fp8(pfA[c], vv3[0], acc[c*8+6], 0, 0, 0);
            acc[c*8+7] = __builtin_amdgcn_mfma_f32_16x16x32_fp8_fp8(pfA[c], vv3[1], acc[c*8+7], 0, 0, 0);
        }

        __syncthreads();   // bar B: V[cur]/P reads done before overwrite
    }

    // epilogue: rows = all 64 q, cols = own 128-d slice
    short* obase = Opart + (((size_t)part * BATCH + b) * SEQ + q0) * 512 + w * 128;
    #pragma unroll
    for (int c = 0; c < 4; ++c)
        #pragma unroll
        for (int dt = 0; dt < 8; ++dt)
            #pragma unroll
            for (int r = 0; r < 4; ++r)
                obase[(size_t)(c * 16 + l4 * 4 + r) * 512 + dt * 16 + l15] = bf16b(acc[c * 8 + dt][r]);
    if (l15 == 0) {
        #pragma unroll
        for (int r = 0; r < 4; ++r) {
            size_t rowg = ((size_t)part * BATCH + b) * SEQ + q0 + w * 16 + l4 * 4 + r;
            ml[rowg * 2]     = mused[r];      // base-2 units
            ml[rowg * 2 + 1] = lacc[r];
        }
    }
}

extern "C" void kernel_launch(void* const* d_in, const int* in_sizes, int n_in,
                              void* d_out, int out_size, void* d_ws, size_t ws_size,
                              hipStream_t stream) {
    const float* x   = (const float*)d_in[0];
    const float* gsc = (const float*)d_in[1];
    const float* gbs = (const float*)d_in[2];
    const float* wq  = (const float*)d_in[3];
    const float* bq  = (const float*)d_in[4];
    const float* wk  = (const float*)d_in[5];
    const float* bk  = (const float*)d_in[6];
    const float* wv  = (const float*)d_in[7];
    const float* bv  = (const float*)d_in[8];
    const float* wo  = (const float*)d_in[9];
    const float* bo  = (const float*)d_in[10];
    float* out = (float*)d_out;

    char* ws = (char*)d_ws;
    const size_t MB = 1ull << 20;
    // [0,16)  xn bf16 (GEMM A input, dead after QKV GEMM)
    // [16,24) q8; [24,32) k8; [32,40) vT8 (fp8, from gemm_qkv epilogue)
    // [40,72) Opart bf16 (2 parts); [72,74) wT; [74,..) stats + ml
    short* xn    = (short*)ws;
    char*  q8    = (char*)(ws + 16 * MB);
    char*  k8    = (char*)(ws + 24 * MB);
    char*  vT8   = (char*)(ws + 32 * MB);
    short* Opart = (short*)(ws + 40 * MB);
    short* wT    = (short*)(ws + 72 * MB);
    float* stats = (float*)(ws + 74 * MB);
    float* ml    = (float*)(ws + 74 * MB + 65536);

    hipMemsetAsync(stats, 0, 256 * sizeof(float), stream);
    gn_partial_kernel<<<256, 256, 0, stream>>>(x, stats);
    gn_apply_kernel<<<8192, 256, 0, stream>>>(x, stats, gsc, gbs, xn);
    wtrans_kernel<<<dim3(16, 16, 4), dim3(32, 8), 0, stream>>>(wq, wk, wv, wo, wT);

    short* woT = wT + 786432;

    gemm_qkv_kernel<<<dim3(128, 12), 256, 0, stream>>>(xn, wT, bq, bk, bv, q8, k8, vT8);
    flash_kernel<<<512, 256, 0, stream>>>(q8, k8, vT8, Opart, ml);
    gemm_bt_kernel<<<dim3(128, 4), 256, 0, stream>>>(Opart, ml, woT, bo, out, x);
}

// Round 7
// 292.603 us; speedup vs baseline: 1.0127x; 1.0127x over previous
//
#include <hip/hip_runtime.h>
#include <hip/hip_bf16.h>
#include <stdint.h>

#define BATCH 4
#define SEQ   4096          // 64*64 spatial
#define CH    512
#define NGRP  32
#define GEPS  1e-6f

typedef short  short8  __attribute__((ext_vector_type(8)));
typedef float  floatx4 __attribute__((ext_vector_type(4)));
typedef long   longx2  __attribute__((ext_vector_type(2)));

static __device__ __forceinline__ short bf16b(float f) {
    __hip_bfloat16 h = __float2bfloat16(f);
    return __builtin_bit_cast(short, h);
}
static __device__ __forceinline__ float bf2f(short s) {
    unsigned u = ((unsigned)(unsigned short)s) << 16;
    return __builtin_bit_cast(float, u);
}
static __device__ __forceinline__ char fp8b(float f) {
    int pk = __builtin_amdgcn_cvt_pk_fp8_f32(f, f, 0, false);
    return (char)(pk & 0xff);
}

// async global->LDS, 16B per lane. LDS dest = wave-uniform base + lane*16.
static __device__ __forceinline__ void dma16(const void* g, void* l) {
    __builtin_amdgcn_global_load_lds(
        (const __attribute__((address_space(1))) unsigned int*)g,
        (__attribute__((address_space(3))) unsigned int*)l, 16, 0, 0);
}

// max-reduce across the 16 lanes of a DPP row, pure VALU
static __device__ __forceinline__ float rowmax16(float x) {
    int xi = __builtin_bit_cast(int, x);
    x = fmaxf(x, __builtin_bit_cast(float, __builtin_amdgcn_update_dpp(xi, xi, 0x128, 0xf, 0xf, true))); // row_ror:8
    xi = __builtin_bit_cast(int, x);
    x = fmaxf(x, __builtin_bit_cast(float, __builtin_amdgcn_update_dpp(xi, xi, 0x124, 0xf, 0xf, true))); // row_ror:4
    xi = __builtin_bit_cast(int, x);
    x = fmaxf(x, __builtin_bit_cast(float, __builtin_amdgcn_update_dpp(xi, xi, 0x122, 0xf, 0xf, true))); // row_ror:2
    xi = __builtin_bit_cast(int, x);
    x = fmaxf(x, __builtin_bit_cast(float, __builtin_amdgcn_update_dpp(xi, xi, 0x121, 0xf, 0xf, true))); // row_ror:1
    return x;
}

// ---------------- GroupNorm partial sums ----------------
__global__ __launch_bounds__(256) void gn_partial_kernel(const float* __restrict__ x,
                                                         float* __restrict__ statsraw) {
    int blk = blockIdx.x;                 // 0..255
    int t = threadIdx.x;
    size_t row0 = (size_t)blk * 64;
    int qd = t & 127;
    int rh = t >> 7;
    const float* base = x + row0 * 512 + qd * 4;
    float s1 = 0.f, s2 = 0.f;
    #pragma unroll 4
    for (int i = 0; i < 32; ++i) {
        int r = rh + i * 2;
        float4 v = *reinterpret_cast<const float4*>(base + (size_t)r * 512);
        s1 += v.x + v.y + v.z + v.w;
        s2 += v.x * v.x + v.y * v.y + v.z * v.z + v.w * v.w;
    }
    __shared__ float a1[256], a2[256];
    a1[t] = s1; a2[t] = s2;
    __syncthreads();
    if (t < 32) {
        float u1 = 0.f, u2 = 0.f;
        #pragma unroll
        for (int e = 0; e < 4; ++e) {
            u1 += a1[t * 4 + e] + a1[128 + t * 4 + e];
            u2 += a2[t * 4 + e] + a2[128 + t * 4 + e];
        }
        int b = (int)(row0 >> 12);
        atomicAdd(&statsraw[(b * 32 + t) * 2],     u1);
        atomicAdd(&statsraw[(b * 32 + t) * 2 + 1], u2);
    }
}

// ---------------- GroupNorm apply ----------------
__global__ __launch_bounds__(256) void gn_apply_kernel(const float* __restrict__ x,
                                                       const float* __restrict__ statsraw,
                                                       const float* __restrict__ gsc,
                                                       const float* __restrict__ gbs,
                                                       short* __restrict__ xn) {
    int i4 = blockIdx.x * 256 + threadIdx.x;
    int base = i4 * 4;
    int b = base >> 21;
    int c = base & 511;
    int sidx = (b * 32 + (c >> 4)) * 2;
    float s1 = statsraw[sidx], s2 = statsraw[sidx + 1];
    float mean = s1 * (1.f / 65536.f);
    float var  = s2 * (1.f / 65536.f) - mean * mean;
    float rstd = rsqrtf(var + GEPS);
    float4 xv = reinterpret_cast<const float4*>(x)[i4];
    float4 sv = *reinterpret_cast<const float4*>(gsc + c);
    float4 bv = *reinterpret_cast<const float4*>(gbs + c);
    union { short s[4]; uint2 u; } p;
    p.s[0] = bf16b((xv.x - mean) * rstd * sv.x + bv.x);
    p.s[1] = bf16b((xv.y - mean) * rstd * sv.y + bv.y);
    p.s[2] = bf16b((xv.z - mean) * rstd * sv.z + bv.z);
    p.s[3] = bf16b((xv.w - mean) * rstd * sv.w + bv.w);
    reinterpret_cast<uint2*>(xn)[i4] = p.u;
}

// ---------------- weight transpose ----------------
__global__ __launch_bounds__(256) void wtrans_kernel(const float* __restrict__ w0,
                                                     const float* __restrict__ w1,
                                                     const float* __restrict__ w2,
                                                     const float* __restrict__ w3,
                                                     short* __restrict__ wT) {
    const float* w = (blockIdx.z == 0) ? w0 : (blockIdx.z == 1) ? w1
                   : (blockIdx.z == 2) ? w2 : w3;
    short* out = wT + (size_t)blockIdx.z * CH * CH;
    int n0 = blockIdx.x * 32, k0 = blockIdx.y * 32;
    int tx = threadIdx.x, ty = threadIdx.y;
    __shared__ float s[32][33];
    #pragma unroll
    for (int i = 0; i < 4; ++i) {
        int kk = ty + i * 8;
        s[kk][tx] = w[(size_t)(k0 + kk) * CH + n0 + tx];
    }
    __syncthreads();
    #pragma unroll
    for (int i = 0; i < 4; ++i) {
        int nn = ty + i * 8;
        out[(size_t)(n0 + nn) * CH + k0 + tx] = bf16b(s[tx][nn]);
    }
}

// ---------------- fused QKV GEMM: fp8 epilogue ------------------------------------
// q8 row-major.
// k8 pair-interleaved tile layout (16KB per 32-row s-block), for flash's paired
//   b128 K reads: byte(b,s,d) = b*2M + (s>>5)*16384 + (s&15)*1024
//                               + (d>>3)*16 + ((s>>4)&1)*8 + (d&7)
//   -> a 16B slot holds chunk d/8 of rows s and s+16.
// vT8 s-col-interleaved (P order) AND pair-interleaved tile layout
//   (16KB per 32-s block): byte(b,d,si) = b*2M + (si>>5)*16384
//     + (((d>>5)*16 + (d&15))*4 + ((si&31)>>3))*16 + ((d>>4)&1)*8 + (si&7)
//   -> a 16B slot holds s-chunk m of rows d and d+16.
__global__ __launch_bounds__(256) void gemm_qkv_kernel(const short* __restrict__ A,
                                                       const short* __restrict__ wT,
                                                       const float* __restrict__ bq,
                                                       const float* __restrict__ bk,
                                                       const float* __restrict__ bv,
                                                       char* __restrict__ q8,
                                                       char* __restrict__ k8,
                                                       char* __restrict__ vT8) {
    __shared__ short As[128 * 64];
    __shared__ short Bs[128 * 64];
    __shared__ char  vls[128 * 144];   // fp8 transpose staging, pitch 144
    int m0 = blockIdx.x * 128;
    int nblk = blockIdx.y;                  // 0..11
    int which = nblk >> 2;                  // 0=q,1=k,2=v (block-uniform)
    int n0 = (nblk & 3) * 128;
    const short* BT = wT + (size_t)which * 512 * 512;
    const float* bias = (which == 0) ? bq : (which == 1) ? bk : bv;
    int t = threadIdx.x;
    int w = t >> 6, lane = t & 63;
    int wr = w >> 1, wc = w & 1;
    int l15 = lane & 15, l4 = lane >> 4;
    floatx4 acc[4][4];
    #pragma unroll
    for (int i = 0; i < 4; ++i)
        #pragma unroll
        for (int j = 0; j < 4; ++j) acc[i][j] = (floatx4){0.f, 0.f, 0.f, 0.f};

    for (int k0 = 0; k0 < 512; k0 += 64) {
        __syncthreads();
        #pragma unroll
        for (int i = 0; i < 4; ++i) {
            int c = i * 256 + t;
            int row = c >> 3, j = (c & 7) ^ (row & 7);
            dma16(&A[(size_t)(m0 + row) * 512 + k0 + j * 8], &As[(c & ~63) * 8]);
            dma16(&BT[(size_t)(n0 + row) * 512 + k0 + j * 8], &Bs[(c & ~63) * 8]);
        }
        __syncthreads();
        #pragma unroll
        for (int kk = 0; kk < 64; kk += 32) {
            short8 af[4], bf[4];
            #pragma unroll
            for (int i = 0; i < 4; ++i) {
                int row = wr * 64 + i * 16 + l15;
                int j = (kk >> 3) + l4;
                af[i] = *reinterpret_cast<const short8*>(&As[(row * 8 + (j ^ (l15 & 7))) * 8]);
            }
            #pragma unroll
            for (int j2 = 0; j2 < 4; ++j2) {
                int row = wc * 64 + j2 * 16 + l15;
                int j = (kk >> 3) + l4;
                bf[j2] = *reinterpret_cast<const short8*>(&Bs[(row * 8 + (j ^ (l15 & 7))) * 8]);
            }
            #pragma unroll
            for (int i = 0; i < 4; ++i)
                #pragma unroll
                for (int j2 = 0; j2 < 4; ++j2)
                    acc[i][j2] = __builtin_amdgcn_mfma_f32_16x16x32_bf16(af[i], bf[j2], acc[i][j2], 0, 0, 0);
        }
    }
    if (which == 0) {
        #pragma unroll
        for (int i = 0; i < 4; ++i)
            #pragma unroll
            for (int j = 0; j < 4; ++j)
                #pragma unroll
                for (int r = 0; r < 4; ++r) {
                    int row = m0 + wr * 64 + i * 16 + l4 * 4 + r;
                    int col = n0 + wc * 64 + j * 16 + l15;
                    q8[(size_t)row * 512 + col] = fp8b(acc[i][j][r] + bias[col]);
                }
    } else if (which == 1) {
        // k8: pair-interleaved tile layout (see header comment)
        #pragma unroll
        for (int i = 0; i < 4; ++i)
            #pragma unroll
            for (int j = 0; j < 4; ++j)
                #pragma unroll
                for (int r = 0; r < 4; ++r) {
                    int row = m0 + wr * 64 + i * 16 + l4 * 4 + r;
                    int col = n0 + wc * 64 + j * 16 + l15;
                    int bb = row >> 12, s = row & 4095;
                    size_t idx = (size_t)bb * 2097152 + (size_t)(s >> 5) * 16384
                               + (s & 15) * 1024 + ((s >> 4) & 1) * 8
                               + (col >> 3) * 16 + (col & 7);
                    k8[idx] = fp8b(acc[i][j][r] + bias[col]);
                }
    } else {
        // v: transpose via LDS, with s-columns pair-interleaved per 32-block
        __syncthreads();
        #pragma unroll
        for (int i = 0; i < 4; ++i)
            #pragma unroll
            for (int j = 0; j < 4; ++j)
                #pragma unroll
                for (int r = 0; r < 4; ++r) {
                    int rl = wr * 64 + i * 16 + l4 * 4 + r;     // local row (sequence)
                    int rp = (rl & ~31) | (((rl & 15) << 1) | ((rl >> 4) & 1));  // interleave
                    int cl = wc * 64 + j * 16 + l15;            // local col (d)
                    vls[cl * 144 + rp] = fp8b(acc[i][j][r] + bias[n0 + cl]);
                }
        __syncthreads();
        int b = m0 >> 12, l0 = m0 & 4095;
        #pragma unroll
        for (int p = 0; p < 4; ++p) {
            int slot = p * 256 + t;
            int c = slot >> 3, off = (slot & 7) * 16;   // off multiple of 16
            uint4 v;
            __builtin_memcpy(&v, &vls[c * 144 + off], 16);
            int dcol = n0 + c;
            int g = dcol >> 5, rr = dcol & 15, h = (dcol >> 4) & 1;
            int s = l0 + off;                    // interleaved s index, mult of 16
            int sb = s >> 5, mb = (s & 31) >> 3; // mb = 0 or 2
            char* dst = vT8 + (size_t)b * 2097152 + (size_t)sb * 16384
                      + (size_t)((((g * 16 + rr) * 4 + mb) * 16) + h * 8);
            unsigned long long lo = ((unsigned long long)v.y << 32) | v.x;
            unsigned long long hi = ((unsigned long long)v.w << 32) | v.z;
            *reinterpret_cast<unsigned long long*>(dst)      = lo;  // chunk mb
            *reinterpret_cast<unsigned long long*>(dst + 16) = hi;  // chunk mb+1
        }
    }
}

// ---------------- output GEMM with FUSED combine: A = merge(Opart0, Opart1, ml) ------
// NOTE: ml max values are in BASE-2 units (flash computes softmax with exp2),
// so the merge uses exp2f.
__global__ __launch_bounds__(256) void gemm_bt_kernel(const short* __restrict__ Opart,
                                                      const float* __restrict__ ml,
                                                      const short* __restrict__ BT,
                                                      const float* __restrict__ bias,
                                                      float* __restrict__ outf,
                                                      const float* __restrict__ resid) {
    __shared__ short As[128 * 64];
    __shared__ short Bs[128 * 64];
    int m0 = blockIdx.x * 128, n0 = blockIdx.y * 128;
    int t = threadIdx.x;
    int w = t >> 6, lane = t & 63;
    int wr = w >> 1, wc = w & 1;
    int l15 = lane & 15, l4 = lane >> 4;
    const size_t PART = (size_t)BATCH * SEQ;   // 16384 rows per part
    floatx4 acc[4][4];
    #pragma unroll
    for (int i = 0; i < 4; ++i)
        #pragma unroll
        for (int j = 0; j < 4; ++j) acc[i][j] = (floatx4){0.f, 0.f, 0.f, 0.f};

    for (int k0 = 0; k0 < 512; k0 += 64) {
        __syncthreads();
        #pragma unroll
        for (int i = 0; i < 4; ++i) {
            int c = i * 256 + t;
            int rl = c >> 3, j = (c & 7) ^ (rl & 7);
            size_t rowg = (size_t)(m0 + rl);
            const short* s0 = Opart + rowg * 512 + k0 + j * 8;
            const short* s1 = s0 + PART * 512;
            uint4 a0 = *reinterpret_cast<const uint4*>(s0);
            uint4 a1 = *reinterpret_cast<const uint4*>(s1);
            float mA = ml[rowg * 2],          lA = ml[rowg * 2 + 1];
            float mB = ml[(PART + rowg) * 2], lB = ml[(PART + rowg) * 2 + 1];
            float mm = fmaxf(mA, mB);
            float e0 = exp2f(mA - mm), e1 = exp2f(mB - mm);
            float inv = 1.f / (e0 * lA + e1 * lB);
            e0 *= inv; e1 *= inv;
            union { uint4 u; short s[8]; } ua, ub, uo;
            ua.u = a0; ub.u = a1;
            #pragma unroll
            for (int e = 0; e < 8; ++e)
                uo.s[e] = bf16b(bf2f(ua.s[e]) * e0 + bf2f(ub.s[e]) * e1);
            *reinterpret_cast<uint4*>(&As[c * 8]) = uo.u;    // ds_write_b128
            dma16(&BT[(size_t)(n0 + rl) * 512 + k0 + j * 8], &Bs[(c & ~63) * 8]);
        }
        __syncthreads();
        #pragma unroll
        for (int kk = 0; kk < 64; kk += 32) {
            short8 af[4], bf[4];
            #pragma unroll
            for (int i = 0; i < 4; ++i) {
                int row = wr * 64 + i * 16 + l15;
                int j = (kk >> 3) + l4;
                af[i] = *reinterpret_cast<const short8*>(&As[(row * 8 + (j ^ (l15 & 7))) * 8]);
            }
            #pragma unroll
            for (int j2 = 0; j2 < 4; ++j2) {
                int row = wc * 64 + j2 * 16 + l15;
                int j = (kk >> 3) + l4;
                bf[j2] = *reinterpret_cast<const short8*>(&Bs[(row * 8 + (j ^ (l15 & 7))) * 8]);
            }
            #pragma unroll
            for (int i = 0; i < 4; ++i)
                #pragma unroll
                for (int j2 = 0; j2 < 4; ++j2)
                    acc[i][j2] = __builtin_amdgcn_mfma_f32_16x16x32_bf16(af[i], bf[j2], acc[i][j2], 0, 0, 0);
        }
    }
    #pragma unroll
    for (int i = 0; i < 4; ++i)
        #pragma unroll
        for (int j = 0; j < 4; ++j)
            #pragma unroll
            for (int r = 0; r < 4; ++r) {
                int row = m0 + wr * 64 + i * 16 + l4 * 4 + r;
                int col = n0 + wc * 64 + j * 16 + l15;
                float vv = acc[i][j][r] + bias[col];
                outf[(size_t)row * 512 + col] = vv + resid[(size_t)row * 512 + col];
            }
}

// ---------------- flash attention: fp8, merged-block (8-wave) round-2 body ----------
// Round-2 per-wave body UNCHANGED (it beat every structural variant in r3-r6).
// The one remaining 2x redundancy: the two blocks co-resident on a CU had the
// same (part,b) (bx&7 == (bx+256)&7) and DMA'd IDENTICAL K/V tiles into two
// separate LDS copies. Merge them: one 512-thread block = 8 waves = 128 q rows,
// 256 blocks = 1 block/CU. Per-CU-iter DMA wave-instrs halve (64->32), LDS
// write cycles and write-side bank conflicts halve (the constant 8.65e6
// conflict count across r2-r6 is attributed to the DMA write stream), HBM
// staging fetch halves. Reads/MFMA/regs per wave unchanged; still 8 waves/CU.
__global__ __launch_bounds__(512, 1) void flash_kernel(const char* __restrict__ q8,
                                                       const char* __restrict__ k8,
                                                       const char* __restrict__ v8,
                                                       short* __restrict__ Opart,
                                                       float* __restrict__ ml) {
    __shared__ __align__(16) char smem[70656];   // K dbuf 32K | V dbuf 32K | P 8x640
    int bx = blockIdx.x;                 // 0..255
    int pb = bx & 7;                     // XCD-local (part,b)
    int part = pb >> 2, b = pb & 3;
    int q0 = (bx >> 3) * 128;            // 128 q rows per block
    int t = threadIdx.x, w = t >> 6, lane = t & 63;   // w = 0..7
    int l15 = lane & 15, l4 = lane >> 4;
    const float c2 = 0.06375873735f;     // (1/sqrt(512)) * log2(e)
    const float MARGIN = 7.2134752f;     // 5*log2(e); p <= 2^7.21 = 148 < 448

    // Q fp8 fragments: rows q0 + w*16 + l15, all 512 k (8 B per ks-step)
    long qf[16];
    {
        const char* qrow = q8 + ((size_t)b * SEQ + q0 + w * 16 + l15) * 512;
        #pragma unroll
        for (int ks = 0; ks < 16; ++ks)
            qf[ks] = *reinterpret_cast<const long*>(qrow + ks * 32 + l4 * 8);
    }

    floatx4 acc[32];
    #pragma unroll
    for (int i = 0; i < 32; ++i) acc[i] = (floatx4){0.f, 0.f, 0.f, 0.f};
    floatx4 lacc = (floatx4){0.f, 0.f, 0.f, 0.f};
    float mused[4] = {-1e30f, -1e30f, -1e30f, -1e30f};

    const long ones = 0x3838383838383838L;   // e4m3 1.0 x8

    const char* kbase = k8 + (size_t)b * SEQ * 512;
    const char* vbase = v8 + (size_t)b * 512 * SEQ;
    const int sb0 = part * 64;           // first 32-s block of this part

    const int ksw = l15 & 7;
    const int vsw = (l15 >> 1) & 3;
    // loop-invariant LDS read bases; per-iter offset = cur*16384 (+ immediates)
    const char* kA_E = smem + ((l15 * 64 + (l4 ^ ksw)) << 4);
    const char* kA_O = smem + ((l15 * 64 + ((4 + l4) ^ ksw)) << 4);
    const char* vA   = smem + 32768 + ((l15 * 4 + (l4 ^ vsw)) << 4);
    char* Ps = smem + 65536 + w * 640;

    // precomputed per-thread DMA source byte-offsets (swizzle folded in).
    // 512 threads -> 2 dma16 each for K (1024 slots) and V.
    int kSrc[2], vSrc[2];
    #pragma unroll
    for (int i = 0; i < 2; ++i) {
        int c = i * 512 + t;
        kSrc[i] = (((c & ~63) | ((c & 63) ^ ((c >> 6) & 7))) << 4);
        vSrc[i] = (((c & ~3)  | ((c & 3)  ^ ((c >> 3) & 3))) << 4);
    }
    const int ldsD = (t & ~63) << 4;   // wave-uniform: w*1024

    auto stage = [&](int sb, int buf) {
        const char* kt = kbase + (size_t)sb * 16384;
        const char* vt = vbase + (size_t)sb * 16384;
        char* Kd = smem + buf * 16384 + ldsD;
        char* Vd = smem + 32768 + buf * 16384 + ldsD;
        #pragma unroll
        for (int i = 0; i < 2; ++i) dma16(kt + kSrc[i], Kd + i * 8192);
        #pragma unroll
        for (int i = 0; i < 2; ++i) dma16(vt + vSrc[i], Vd + i * 8192);
    };

    stage(sb0, 0);
    __syncthreads();                                   // tile 0 ready

    for (int it = 0; it < 64; ++it) {
        int cur = it & 1;
        int coff = cur << 14;
        if (it + 1 < 64) stage(sb0 + it + 1, 1 - cur);

        // --- QK^T (fp8): one b128 per pair: low 8B = K row l15, high = l15+16
        floatx4 sa0 = (floatx4){0.f, 0.f, 0.f, 0.f};
        floatx4 sa1 = (floatx4){0.f, 0.f, 0.f, 0.f};
        #pragma unroll
        for (int j = 0; j < 8; ++j) {
            longx2 kE = *reinterpret_cast<const longx2*>(kA_E + coff + j * 128);
            longx2 kO = *reinterpret_cast<const longx2*>(kA_O + coff + j * 128);
            sa0 = __builtin_amdgcn_mfma_f32_16x16x32_fp8_fp8(qf[2 * j],     kE[0], sa0, 0, 0, 0);
            sa1 = __builtin_amdgcn_mfma_f32_16x16x32_fp8_fp8(qf[2 * j],     kE[1], sa1, 0, 0, 0);
            sa0 = __builtin_amdgcn_mfma_f32_16x16x32_fp8_fp8(qf[2 * j + 1], kO[0], sa0, 0, 0, 0);
            sa1 = __builtin_amdgcn_mfma_f32_16x16x32_fp8_fp8(qf[2 * j + 1], kO[1], sa1, 0, 0, 0);
        }

        // --- online softmax, base-2, lazy rescale
        float v0[4], v1[4], nm4[4];
        bool need = false;
        #pragma unroll
        for (int r = 0; r < 4; ++r) {
            v0[r] = sa0[r] * c2; v1[r] = sa1[r] * c2;
            nm4[r] = rowmax16(fmaxf(v0[r], v1[r]));
            need |= (nm4[r] > mused[r] + MARGIN);
        }
        if (__ballot(need)) {
            #pragma unroll
            for (int r = 0; r < 4; ++r) {
                float nm = fmaxf(mused[r], nm4[r]);
                float al = exp2f(mused[r] - nm);
                lacc[r] *= al;
                #pragma unroll
                for (int i = 0; i < 32; ++i) acc[i][r] *= al;
                mused[r] = nm;
            }
        }
        // P (fp8) write: interleaved col pairs (c, c+16) -> mem cols (2c, 2c+1).
        #pragma unroll
        for (int r = 0; r < 4; ++r) {
            int pk = __builtin_amdgcn_cvt_pk_fp8_f32(exp2f(v0[r] - mused[r]),
                                                     exp2f(v1[r] - mused[r]), 0, false);
            *reinterpret_cast<short*>(Ps + (l4 * 4 + r) * 40 + l15 * 2) = (short)pk;
        }

        // A-frag read via memcpy (may-alias pun -> ordered AFTER the short stores)
        long pf;
        __builtin_memcpy(&pf, (const char*)__builtin_assume_aligned(Ps + l15 * 40 + l4 * 8, 8), 8);
        lacc = __builtin_amdgcn_mfma_f32_16x16x32_fp8_fp8(pf, ones, lacc, 0, 0, 0);
        // --- PV: one b128 per pair: low 8B = V row d, high 8B = V row d+16.
        #pragma unroll
        for (int g = 0; g < 16; ++g) {
            longx2 vv = *reinterpret_cast<const longx2*>(vA + coff + g * 1024);
            acc[2 * g]     = __builtin_amdgcn_mfma_f32_16x16x32_fp8_fp8(pf, vv[0], acc[2 * g],     0, 0, 0);
            acc[2 * g + 1] = __builtin_amdgcn_mfma_f32_16x16x32_fp8_fp8(pf, vv[1], acc[2 * g + 1], 0, 0, 0);
        }

        __syncthreads();    // drains DMA(it+1) + all reads of buf[cur] done
    }

    short* obase = Opart + (((size_t)part * BATCH + b) * SEQ + q0 + w * 16) * 512;
    #pragma unroll
    for (int r = 0; r < 4; ++r) {
        #pragma unroll
        for (int tt = 0; tt < 32; ++tt)
            obase[(size_t)(l4 * 4 + r) * 512 + tt * 16 + l15] = bf16b(acc[tt][r]);
    }
    if (l15 == 0) {
        #pragma unroll
        for (int r = 0; r < 4; ++r) {
            size_t rowg = ((size_t)part * BATCH + b) * SEQ + q0 + w * 16 + l4 * 4 + r;
            ml[rowg * 2]     = mused[r];      // base-2 units
            ml[rowg * 2 + 1] = lacc[r];
        }
    }
}

extern "C" void kernel_launch(void* const* d_in, const int* in_sizes, int n_in,
                              void* d_out, int out_size, void* d_ws, size_t ws_size,
                              hipStream_t stream) {
    const float* x   = (const float*)d_in[0];
    const float* gsc = (const float*)d_in[1];
    const float* gbs = (const float*)d_in[2];
    const float* wq  = (const float*)d_in[3];
    const float* bq  = (const float*)d_in[4];
    const float* wk  = (const float*)d_in[5];
    const float* bk  = (const float*)d_in[6];
    const float* wv  = (const float*)d_in[7];
    const float* bv  = (const float*)d_in[8];
    const float* wo  = (const float*)d_in[9];
    const float* bo  = (const float*)d_in[10];
    float* out = (float*)d_out;

    char* ws = (char*)d_ws;
    const size_t MB = 1ull << 20;
    // [0,16)  xn bf16 (GEMM A input, dead after QKV GEMM)
    // [16,24) q8; [24,32) k8; [32,40) vT8 (fp8, from gemm_qkv epilogue)
    // [40,72) Opart bf16 (2 parts); [72,74) wT; [74,..) stats + ml
    short* xn    = (short*)ws;
    char*  q8    = (char*)(ws + 16 * MB);
    char*  k8    = (char*)(ws + 24 * MB);
    char*  vT8   = (char*)(ws + 32 * MB);
    short* Opart = (short*)(ws + 40 * MB);
    short* wT    = (short*)(ws + 72 * MB);
    float* stats = (float*)(ws + 74 * MB);
    float* ml    = (float*)(ws + 74 * MB + 65536);

    hipMemsetAsync(stats, 0, 256 * sizeof(float), stream);
    gn_partial_kernel<<<256, 256, 0, stream>>>(x, stats);
    gn_apply_kernel<<<8192, 256, 0, stream>>>(x, stats, gsc, gbs, xn);
    wtrans_kernel<<<dim3(16, 16, 4), dim3(32, 8), 0, stream>>>(wq, wk, wv, wo, wT);

    short* woT = wT + 786432;

    gemm_qkv_kernel<<<dim3(128, 12), 256, 0, stream>>>(xn, wT, bq, bk, bv, q8, k8, vT8);
    flash_kernel<<<256, 512, 0, stream>>>(q8, k8, vT8, Opart, ml);
    gemm_bt_kernel<<<dim3(128, 4), 256, 0, stream>>>(Opart, ml, woT, bo, out, x);
}

// Round 8
// 288.772 us; speedup vs baseline: 1.0261x; 1.0133x over previous
//
#include <hip/hip_runtime.h>
#include <hip/hip_bf16.h>
#include <stdint.h>

#define BATCH 4
#define SEQ   4096          // 64*64 spatial
#define CH    512
#define NGRP  32
#define GEPS  1e-6f

typedef short  short8  __attribute__((ext_vector_type(8)));
typedef float  floatx4 __attribute__((ext_vector_type(4)));
typedef long   longx2  __attribute__((ext_vector_type(2)));

static __device__ __forceinline__ short bf16b(float f) {
    __hip_bfloat16 h = __float2bfloat16(f);
    return __builtin_bit_cast(short, h);
}
static __device__ __forceinline__ float bf2f(short s) {
    unsigned u = ((unsigned)(unsigned short)s) << 16;
    return __builtin_bit_cast(float, u);
}
static __device__ __forceinline__ char fp8b(float f) {
    int pk = __builtin_amdgcn_cvt_pk_fp8_f32(f, f, 0, false);
    return (char)(pk & 0xff);
}

// async global->LDS, 16B per lane. LDS dest = wave-uniform base + lane*16.
static __device__ __forceinline__ void dma16(const void* g, void* l) {
    __builtin_amdgcn_global_load_lds(
        (const __attribute__((address_space(1))) unsigned int*)g,
        (__attribute__((address_space(3))) unsigned int*)l, 16, 0, 0);
}

// max-reduce across the 16 lanes of a DPP row, pure VALU
static __device__ __forceinline__ float rowmax16(float x) {
    int xi = __builtin_bit_cast(int, x);
    x = fmaxf(x, __builtin_bit_cast(float, __builtin_amdgcn_update_dpp(xi, xi, 0x128, 0xf, 0xf, true))); // row_ror:8
    xi = __builtin_bit_cast(int, x);
    x = fmaxf(x, __builtin_bit_cast(float, __builtin_amdgcn_update_dpp(xi, xi, 0x124, 0xf, 0xf, true))); // row_ror:4
    xi = __builtin_bit_cast(int, x);
    x = fmaxf(x, __builtin_bit_cast(float, __builtin_amdgcn_update_dpp(xi, xi, 0x122, 0xf, 0xf, true))); // row_ror:2
    xi = __builtin_bit_cast(int, x);
    x = fmaxf(x, __builtin_bit_cast(float, __builtin_amdgcn_update_dpp(xi, xi, 0x121, 0xf, 0xf, true))); // row_ror:1
    return x;
}

// ---------------- fused GroupNorm partial sums + weight transpose ----------------
// blocks 0..255: GN partial sums (unchanged body).
// blocks 256..1279: wtrans (1024 blocks = 16 x 16 x 4), 2D thread remap.
// Block-uniform branch; saves one kernel dispatch.
__global__ __launch_bounds__(256) void gn_wt_kernel(const float* __restrict__ x,
                                                    float* __restrict__ statsraw,
                                                    const float* __restrict__ w0,
                                                    const float* __restrict__ w1,
                                                    const float* __restrict__ w2,
                                                    const float* __restrict__ w3,
                                                    short* __restrict__ wT) {
    __shared__ float a1[256], a2[256];
    __shared__ float trs[32][33];
    int blk = blockIdx.x;
    int t = threadIdx.x;
    if (blk < 256) {
        size_t row0 = (size_t)blk * 64;
        int qd = t & 127;
        int rh = t >> 7;
        const float* base = x + row0 * 512 + qd * 4;
        float s1 = 0.f, s2 = 0.f;
        #pragma unroll 4
        for (int i = 0; i < 32; ++i) {
            int r = rh + i * 2;
            float4 v = *reinterpret_cast<const float4*>(base + (size_t)r * 512);
            s1 += v.x + v.y + v.z + v.w;
            s2 += v.x * v.x + v.y * v.y + v.z * v.z + v.w * v.w;
        }
        a1[t] = s1; a2[t] = s2;
        __syncthreads();
        if (t < 32) {
            float u1 = 0.f, u2 = 0.f;
            #pragma unroll
            for (int e = 0; e < 4; ++e) {
                u1 += a1[t * 4 + e] + a1[128 + t * 4 + e];
                u2 += a2[t * 4 + e] + a2[128 + t * 4 + e];
            }
            int b = (int)(row0 >> 12);
            atomicAdd(&statsraw[(b * 32 + t) * 2],     u1);
            atomicAdd(&statsraw[(b * 32 + t) * 2 + 1], u2);
        }
    } else {
        int bz = (blk - 256) >> 8;
        int rem = (blk - 256) & 255;
        int n0 = (rem & 15) * 32, k0 = (rem >> 4) * 32;
        const float* w = (bz == 0) ? w0 : (bz == 1) ? w1 : (bz == 2) ? w2 : w3;
        short* out = wT + (size_t)bz * CH * CH;
        int tx = t & 31, ty = t >> 5;
        #pragma unroll
        for (int i = 0; i < 4; ++i) {
            int kk = ty + i * 8;
            trs[kk][tx] = w[(size_t)(k0 + kk) * CH + n0 + tx];
        }
        __syncthreads();
        #pragma unroll
        for (int i = 0; i < 4; ++i) {
            int nn = ty + i * 8;
            out[(size_t)(n0 + nn) * CH + k0 + tx] = bf16b(trs[tx][nn]);
        }
    }
}

// ---------------- GroupNorm apply ----------------
__global__ __launch_bounds__(256) void gn_apply_kernel(const float* __restrict__ x,
                                                       const float* __restrict__ statsraw,
                                                       const float* __restrict__ gsc,
                                                       const float* __restrict__ gbs,
                                                       short* __restrict__ xn) {
    int i4 = blockIdx.x * 256 + threadIdx.x;
    int base = i4 * 4;
    int b = base >> 21;
    int c = base & 511;
    int sidx = (b * 32 + (c >> 4)) * 2;
    float s1 = statsraw[sidx], s2 = statsraw[sidx + 1];
    float mean = s1 * (1.f / 65536.f);
    float var  = s2 * (1.f / 65536.f) - mean * mean;
    float rstd = rsqrtf(var + GEPS);
    float4 xv = reinterpret_cast<const float4*>(x)[i4];
    float4 sv = *reinterpret_cast<const float4*>(gsc + c);
    float4 bv = *reinterpret_cast<const float4*>(gbs + c);
    union { short s[4]; uint2 u; } p;
    p.s[0] = bf16b((xv.x - mean) * rstd * sv.x + bv.x);
    p.s[1] = bf16b((xv.y - mean) * rstd * sv.y + bv.y);
    p.s[2] = bf16b((xv.z - mean) * rstd * sv.z + bv.z);
    p.s[3] = bf16b((xv.w - mean) * rstd * sv.w + bv.w);
    reinterpret_cast<uint2*>(xn)[i4] = p.u;
}

// ---------------- fused QKV GEMM: fp8 epilogue ------------------------------------
// q8 row-major.
// k8 pair-interleaved tile layout (16KB per 32-row s-block), for flash's paired
//   b128 K reads: byte(b,s,d) = b*2M + (s>>5)*16384 + (s&15)*1024
//                               + (d>>3)*16 + ((s>>4)&1)*8 + (d&7)
// vT8 s-col-interleaved (P order) AND pair-interleaved tile layout
//   (16KB per 32-s block): byte(b,d,si) = b*2M + (si>>5)*16384
//     + (((d>>5)*16 + (d&15))*4 + ((si&31)>>3))*16 + ((d>>4)&1)*8 + (si&7)
// ALL three outputs now go through vls LDS staging -> coalesced uint4 stores
// (old q8/k8 paths were 64 global_store_byte per thread).
__global__ __launch_bounds__(256) void gemm_qkv_kernel(const short* __restrict__ A,
                                                       const short* __restrict__ wT,
                                                       const float* __restrict__ bq,
                                                       const float* __restrict__ bk,
                                                       const float* __restrict__ bv,
                                                       char* __restrict__ q8,
                                                       char* __restrict__ k8,
                                                       char* __restrict__ vT8) {
    __shared__ short As[128 * 64];
    __shared__ short Bs[128 * 64];
    __shared__ char  vls[128 * 144];   // fp8 store-staging, 18KB
    int m0 = blockIdx.x * 128;
    int nblk = blockIdx.y;                  // 0..11
    int which = nblk >> 2;                  // 0=q,1=k,2=v (block-uniform)
    int n0 = (nblk & 3) * 128;
    const short* BT = wT + (size_t)which * 512 * 512;
    const float* bias = (which == 0) ? bq : (which == 1) ? bk : bv;
    int t = threadIdx.x;
    int w = t >> 6, lane = t & 63;
    int wr = w >> 1, wc = w & 1;
    int l15 = lane & 15, l4 = lane >> 4;
    floatx4 acc[4][4];
    #pragma unroll
    for (int i = 0; i < 4; ++i)
        #pragma unroll
        for (int j = 0; j < 4; ++j) acc[i][j] = (floatx4){0.f, 0.f, 0.f, 0.f};

    for (int k0 = 0; k0 < 512; k0 += 64) {
        __syncthreads();
        #pragma unroll
        for (int i = 0; i < 4; ++i) {
            int c = i * 256 + t;
            int row = c >> 3, j = (c & 7) ^ (row & 7);
            dma16(&A[(size_t)(m0 + row) * 512 + k0 + j * 8], &As[(c & ~63) * 8]);
            dma16(&BT[(size_t)(n0 + row) * 512 + k0 + j * 8], &Bs[(c & ~63) * 8]);
        }
        __syncthreads();
        #pragma unroll
        for (int kk = 0; kk < 64; kk += 32) {
            short8 af[4], bf[4];
            #pragma unroll
            for (int i = 0; i < 4; ++i) {
                int row = wr * 64 + i * 16 + l15;
                int j = (kk >> 3) + l4;
                af[i] = *reinterpret_cast<const short8*>(&As[(row * 8 + (j ^ (l15 & 7))) * 8]);
            }
            #pragma unroll
            for (int j2 = 0; j2 < 4; ++j2) {
                int row = wc * 64 + j2 * 16 + l15;
                int j = (kk >> 3) + l4;
                bf[j2] = *reinterpret_cast<const short8*>(&Bs[(row * 8 + (j ^ (l15 & 7))) * 8]);
            }
            #pragma unroll
            for (int i = 0; i < 4; ++i)
                #pragma unroll
                for (int j2 = 0; j2 < 4; ++j2)
                    acc[i][j2] = __builtin_amdgcn_mfma_f32_16x16x32_bf16(af[i], bf[j2], acc[i][j2], 0, 0, 0);
        }
    }
    if (which == 0) {
        // q8: stage row-major into vls (pitch 144), then coalesced uint4 stores
        #pragma unroll
        for (int i = 0; i < 4; ++i)
            #pragma unroll
            for (int j = 0; j < 4; ++j)
                #pragma unroll
                for (int r = 0; r < 4; ++r) {
                    int rl = wr * 64 + i * 16 + l4 * 4 + r;
                    int cl = wc * 64 + j * 16 + l15;
                    vls[rl * 144 + cl] = fp8b(acc[i][j][r] + bias[n0 + cl]);
                }
        __syncthreads();
        #pragma unroll
        for (int p = 0; p < 4; ++p) {
            int slot = p * 256 + t;
            int c = slot >> 3, off = (slot & 7) * 16;
            uint4 v;
            __builtin_memcpy(&v, &vls[c * 144 + off], 16);
            *reinterpret_cast<uint4*>(&q8[(size_t)(m0 + c) * 512 + n0 + off]) = v;
        }
    } else if (which == 1) {
        // k8: stage exact global-tile image into vls (ch XOR-swizzled against
        // staging-write bank conflicts), then coalesced uint4 stores.
        // unit(sblk, srow, ch) = 16B holding d-chunk ch for s=srow and s=srow+16.
        #pragma unroll
        for (int i = 0; i < 4; ++i)
            #pragma unroll
            for (int j = 0; j < 4; ++j)
                #pragma unroll
                for (int r = 0; r < 4; ++r) {
                    int rl = wr * 64 + i * 16 + l4 * 4 + r;
                    int cl = wc * 64 + j * 16 + l15;
                    int sblk = rl >> 5, srow = rl & 15, hp = (rl >> 4) & 1;
                    int ch = (cl >> 3) ^ (srow & 7);
                    vls[sblk * 4096 + srow * 256 + ch * 16 + hp * 8 + (cl & 7)]
                        = fp8b(acc[i][j][r] + bias[n0 + cl]);
                }
        __syncthreads();
        int bb = m0 >> 12, sb0 = (m0 & 4095) >> 5;
        #pragma unroll
        for (int p = 0; p < 4; ++p) {
            int u = p * 256 + t;
            int sblk = u >> 8, srow = (u >> 4) & 15, ch = u & 15;
            uint4 v;
            __builtin_memcpy(&v, &vls[sblk * 4096 + srow * 256 + ((ch ^ (srow & 7)) * 16)], 16);
            char* dst = k8 + (size_t)bb * 2097152 + (size_t)(sb0 + sblk) * 16384
                      + srow * 1024 + n0 * 2 + ch * 16;
            *reinterpret_cast<uint4*>(dst) = v;
        }
    } else {
        // v: transpose via LDS, with s-columns pair-interleaved per 32-block
        __syncthreads();
        #pragma unroll
        for (int i = 0; i < 4; ++i)
            #pragma unroll
            for (int j = 0; j < 4; ++j)
                #pragma unroll
                for (int r = 0; r < 4; ++r) {
                    int rl = wr * 64 + i * 16 + l4 * 4 + r;     // local row (sequence)
                    int rp = (rl & ~31) | (((rl & 15) << 1) | ((rl >> 4) & 1));  // interleave
                    int cl = wc * 64 + j * 16 + l15;            // local col (d)
                    vls[cl * 144 + rp] = fp8b(acc[i][j][r] + bias[n0 + cl]);
                }
        __syncthreads();
        int b = m0 >> 12, l0 = m0 & 4095;
        #pragma unroll
        for (int p = 0; p < 4; ++p) {
            int slot = p * 256 + t;
            int c = slot >> 3, off = (slot & 7) * 16;   // off multiple of 16
            uint4 v;
            __builtin_memcpy(&v, &vls[c * 144 + off], 16);
            int dcol = n0 + c;
            int g = dcol >> 5, rr = dcol & 15, h = (dcol >> 4) & 1;
            int s = l0 + off;                    // interleaved s index, mult of 16
            int sb = s >> 5, mb = (s & 31) >> 3; // mb = 0 or 2
            char* dst = vT8 + (size_t)b * 2097152 + (size_t)sb * 16384
                      + (size_t)((((g * 16 + rr) * 4 + mb) * 16) + h * 8);
            unsigned long long lo = ((unsigned long long)v.y << 32) | v.x;
            unsigned long long hi = ((unsigned long long)v.w << 32) | v.z;
            *reinterpret_cast<unsigned long long*>(dst)      = lo;  // chunk mb
            *reinterpret_cast<unsigned long long*>(dst + 16) = hi;  // chunk mb+1
        }
    }
}

// ---------------- output GEMM with FUSED combine: A = merge(Opart0, Opart1, ml) ------
// NOTE: ml max values are in BASE-2 units (flash computes softmax with exp2),
// so the merge uses exp2f.
__global__ __launch_bounds__(256) void gemm_bt_kernel(const short* __restrict__ Opart,
                                                      const float* __restrict__ ml,
                                                      const short* __restrict__ BT,
                                                      const float* __restrict__ bias,
                                                      float* __restrict__ outf,
                                                      const float* __restrict__ resid) {
    __shared__ short As[128 * 64];
    __shared__ short Bs[128 * 64];
    int m0 = blockIdx.x * 128, n0 = blockIdx.y * 128;
    int t = threadIdx.x;
    int w = t >> 6, lane = t & 63;
    int wr = w >> 1, wc = w & 1;
    int l15 = lane & 15, l4 = lane >> 4;
    const size_t PART = (size_t)BATCH * SEQ;   // 16384 rows per part
    floatx4 acc[4][4];
    #pragma unroll
    for (int i = 0; i < 4; ++i)
        #pragma unroll
        for (int j = 0; j < 4; ++j) acc[i][j] = (floatx4){0.f, 0.f, 0.f, 0.f};

    for (int k0 = 0; k0 < 512; k0 += 64) {
        __syncthreads();
        #pragma unroll
        for (int i = 0; i < 4; ++i) {
            int c = i * 256 + t;
            int rl = c >> 3, j = (c & 7) ^ (rl & 7);
            size_t rowg = (size_t)(m0 + rl);
            const short* s0 = Opart + rowg * 512 + k0 + j * 8;
            const short* s1 = s0 + PART * 512;
            uint4 a0 = *reinterpret_cast<const uint4*>(s0);
            uint4 a1 = *reinterpret_cast<const uint4*>(s1);
            float mA = ml[rowg * 2],          lA = ml[rowg * 2 + 1];
            float mB = ml[(PART + rowg) * 2], lB = ml[(PART + rowg) * 2 + 1];
            float mm = fmaxf(mA, mB);
            float e0 = exp2f(mA - mm), e1 = exp2f(mB - mm);
            float inv = 1.f / (e0 * lA + e1 * lB);
            e0 *= inv; e1 *= inv;
            union { uint4 u; short s[8]; } ua, ub, uo;
            ua.u = a0; ub.u = a1;
            #pragma unroll
            for (int e = 0; e < 8; ++e)
                uo.s[e] = bf16b(bf2f(ua.s[e]) * e0 + bf2f(ub.s[e]) * e1);
            *reinterpret_cast<uint4*>(&As[c * 8]) = uo.u;    // ds_write_b128
            dma16(&BT[(size_t)(n0 + rl) * 512 + k0 + j * 8], &Bs[(c & ~63) * 8]);
        }
        __syncthreads();
        #pragma unroll
        for (int kk = 0; kk < 64; kk += 32) {
            short8 af[4], bf[4];
            #pragma unroll
            for (int i = 0; i < 4; ++i) {
                int row = wr * 64 + i * 16 + l15;
                int j = (kk >> 3) + l4;
                af[i] = *reinterpret_cast<const short8*>(&As[(row * 8 + (j ^ (l15 & 7))) * 8]);
            }
            #pragma unroll
            for (int j2 = 0; j2 < 4; ++j2) {
                int row = wc * 64 + j2 * 16 + l15;
                int j = (kk >> 3) + l4;
                bf[j2] = *reinterpret_cast<const short8*>(&Bs[(row * 8 + (j ^ (l15 & 7))) * 8]);
            }
            #pragma unroll
            for (int i = 0; i < 4; ++i)
                #pragma unroll
                for (int j2 = 0; j2 < 4; ++j2)
                    acc[i][j2] = __builtin_amdgcn_mfma_f32_16x16x32_bf16(af[i], bf[j2], acc[i][j2], 0, 0, 0);
        }
    }
    #pragma unroll
    for (int i = 0; i < 4; ++i)
        #pragma unroll
        for (int j = 0; j < 4; ++j)
            #pragma unroll
            for (int r = 0; r < 4; ++r) {
                int row = m0 + wr * 64 + i * 16 + l4 * 4 + r;
                int col = n0 + wc * 64 + j * 16 + l15;
                float vv = acc[i][j][r] + bias[col];
                outf[(size_t)row * 512 + col] = vv + resid[(size_t)row * 512 + col];
            }
}

// ---------------- flash attention: fp8, merged-block (8-wave) round-2 body ----------
// VERBATIM round-7 kernel (134.5 us; survived 6 attack angles — local optimum).
__global__ __launch_bounds__(512, 1) void flash_kernel(const char* __restrict__ q8,
                                                       const char* __restrict__ k8,
                                                       const char* __restrict__ v8,
                                                       short* __restrict__ Opart,
                                                       float* __restrict__ ml) {
    __shared__ __align__(16) char smem[70656];   // K dbuf 32K | V dbuf 32K | P 8x640
    int bx = blockIdx.x;                 // 0..255
    int pb = bx & 7;                     // XCD-local (part,b)
    int part = pb >> 2, b = pb & 3;
    int q0 = (bx >> 3) * 128;            // 128 q rows per block
    int t = threadIdx.x, w = t >> 6, lane = t & 63;   // w = 0..7
    int l15 = lane & 15, l4 = lane >> 4;
    const float c2 = 0.06375873735f;     // (1/sqrt(512)) * log2(e)
    const float MARGIN = 7.2134752f;     // 5*log2(e); p <= 2^7.21 = 148 < 448

    // Q fp8 fragments: rows q0 + w*16 + l15, all 512 k (8 B per ks-step)
    long qf[16];
    {
        const char* qrow = q8 + ((size_t)b * SEQ + q0 + w * 16 + l15) * 512;
        #pragma unroll
        for (int ks = 0; ks < 16; ++ks)
            qf[ks] = *reinterpret_cast<const long*>(qrow + ks * 32 + l4 * 8);
    }

    floatx4 acc[32];
    #pragma unroll
    for (int i = 0; i < 32; ++i) acc[i] = (floatx4){0.f, 0.f, 0.f, 0.f};
    floatx4 lacc = (floatx4){0.f, 0.f, 0.f, 0.f};
    float mused[4] = {-1e30f, -1e30f, -1e30f, -1e30f};

    const long ones = 0x3838383838383838L;   // e4m3 1.0 x8

    const char* kbase = k8 + (size_t)b * SEQ * 512;
    const char* vbase = v8 + (size_t)b * 512 * SEQ;
    const int sb0 = part * 64;           // first 32-s block of this part

    const int ksw = l15 & 7;
    const int vsw = (l15 >> 1) & 3;
    // loop-invariant LDS read bases; per-iter offset = cur*16384 (+ immediates)
    const char* kA_E = smem + ((l15 * 64 + (l4 ^ ksw)) << 4);
    const char* kA_O = smem + ((l15 * 64 + ((4 + l4) ^ ksw)) << 4);
    const char* vA   = smem + 32768 + ((l15 * 4 + (l4 ^ vsw)) << 4);
    char* Ps = smem + 65536 + w * 640;

    // precomputed per-thread DMA source byte-offsets (swizzle folded in).
    // 512 threads -> 2 dma16 each for K (1024 slots) and V.
    int kSrc[2], vSrc[2];
    #pragma unroll
    for (int i = 0; i < 2; ++i) {
        int c = i * 512 + t;
        kSrc[i] = (((c & ~63) | ((c & 63) ^ ((c >> 6) & 7))) << 4);
        vSrc[i] = (((c & ~3)  | ((c & 3)  ^ ((c >> 3) & 3))) << 4);
    }
    const int ldsD = (t & ~63) << 4;   // wave-uniform: w*1024

    auto stage = [&](int sb, int buf) {
        const char* kt = kbase + (size_t)sb * 16384;
        const char* vt = vbase + (size_t)sb * 16384;
        char* Kd = smem + buf * 16384 + ldsD;
        char* Vd = smem + 32768 + buf * 16384 + ldsD;
        #pragma unroll
        for (int i = 0; i < 2; ++i) dma16(kt + kSrc[i], Kd + i * 8192);
        #pragma unroll
        for (int i = 0; i < 2; ++i) dma16(vt + vSrc[i], Vd + i * 8192);
    };

    stage(sb0, 0);
    __syncthreads();                                   // tile 0 ready

    for (int it = 0; it < 64; ++it) {
        int cur = it & 1;
        int coff = cur << 14;
        if (it + 1 < 64) stage(sb0 + it + 1, 1 - cur);

        // --- QK^T (fp8): one b128 per pair: low 8B = K row l15, high = l15+16
        floatx4 sa0 = (floatx4){0.f, 0.f, 0.f, 0.f};
        floatx4 sa1 = (floatx4){0.f, 0.f, 0.f, 0.f};
        #pragma unroll
        for (int j = 0; j < 8; ++j) {
            longx2 kE = *reinterpret_cast<const longx2*>(kA_E + coff + j * 128);
            longx2 kO = *reinterpret_cast<const longx2*>(kA_O + coff + j * 128);
            sa0 = __builtin_amdgcn_mfma_f32_16x16x32_fp8_fp8(qf[2 * j],     kE[0], sa0, 0, 0, 0);
            sa1 = __builtin_amdgcn_mfma_f32_16x16x32_fp8_fp8(qf[2 * j],     kE[1], sa1, 0, 0, 0);
            sa0 = __builtin_amdgcn_mfma_f32_16x16x32_fp8_fp8(qf[2 * j + 1], kO[0], sa0, 0, 0, 0);
            sa1 = __builtin_amdgcn_mfma_f32_16x16x32_fp8_fp8(qf[2 * j + 1], kO[1], sa1, 0, 0, 0);
        }

        // --- online softmax, base-2, lazy rescale
        float v0[4], v1[4], nm4[4];
        bool need = false;
        #pragma unroll
        for (int r = 0; r < 4; ++r) {
            v0[r] = sa0[r] * c2; v1[r] = sa1[r] * c2;
            nm4[r] = rowmax16(fmaxf(v0[r], v1[r]));
            need |= (nm4[r] > mused[r] + MARGIN);
        }
        if (__ballot(need)) {
            #pragma unroll
            for (int r = 0; r < 4; ++r) {
                float nm = fmaxf(mused[r], nm4[r]);
                float al = exp2f(mused[r] - nm);
                lacc[r] *= al;
                #pragma unroll
                for (int i = 0; i < 32; ++i) acc[i][r] *= al;
                mused[r] = nm;
            }
        }
        // P (fp8) write: interleaved col pairs (c, c+16) -> mem cols (2c, 2c+1).
        #pragma unroll
        for (int r = 0; r < 4; ++r) {
            int pk = __builtin_amdgcn_cvt_pk_fp8_f32(exp2f(v0[r] - mused[r]),
                                                     exp2f(v1[r] - mused[r]), 0, false);
            *reinterpret_cast<short*>(Ps + (l4 * 4 + r) * 40 + l15 * 2) = (short)pk;
        }

        // A-frag read via memcpy (may-alias pun -> ordered AFTER the short stores)
        long pf;
        __builtin_memcpy(&pf, (const char*)__builtin_assume_aligned(Ps + l15 * 40 + l4 * 8, 8), 8);
        lacc = __builtin_amdgcn_mfma_f32_16x16x32_fp8_fp8(pf, ones, lacc, 0, 0, 0);
        // --- PV: one b128 per pair: low 8B = V row d, high 8B = V row d+16.
        #pragma unroll
        for (int g = 0; g < 16; ++g) {
            longx2 vv = *reinterpret_cast<const longx2*>(vA + coff + g * 1024);
            acc[2 * g]     = __builtin_amdgcn_mfma_f32_16x16x32_fp8_fp8(pf, vv[0], acc[2 * g],     0, 0, 0);
            acc[2 * g + 1] = __builtin_amdgcn_mfma_f32_16x16x32_fp8_fp8(pf, vv[1], acc[2 * g + 1], 0, 0, 0);
        }

        __syncthreads();    // drains DMA(it+1) + all reads of buf[cur] done
    }

    short* obase = Opart + (((size_t)part * BATCH + b) * SEQ + q0 + w * 16) * 512;
    #pragma unroll
    for (int r = 0; r < 4; ++r) {
        #pragma unroll
        for (int tt = 0; tt < 32; ++tt)
            obase[(size_t)(l4 * 4 + r) * 512 + tt * 16 + l15] = bf16b(acc[tt][r]);
    }
    if (l15 == 0) {
        #pragma unroll
        for (int r = 0; r < 4; ++r) {
            size_t rowg = ((size_t)part * BATCH + b) * SEQ + q0 + w * 16 + l4 * 4 + r;
            ml[rowg * 2]     = mused[r];      // base-2 units
            ml[rowg * 2 + 1] = lacc[r];
        }
    }
}

extern "C" void kernel_launch(void* const* d_in, const int* in_sizes, int n_in,
                              void* d_out, int out_size, void* d_ws, size_t ws_size,
                              hipStream_t stream) {
    const float* x   = (const float*)d_in[0];
    const float* gsc = (const float*)d_in[1];
    const float* gbs = (const float*)d_in[2];
    const float* wq  = (const float*)d_in[3];
    const float* bq  = (const float*)d_in[4];
    const float* wk  = (const float*)d_in[5];
    const float* bk  = (const float*)d_in[6];
    const float* wv  = (const float*)d_in[7];
    const float* bv  = (const float*)d_in[8];
    const float* wo  = (const float*)d_in[9];
    const float* bo  = (const float*)d_in[10];
    float* out = (float*)d_out;

    char* ws = (char*)d_ws;
    const size_t MB = 1ull << 20;
    // [0,16)  xn bf16 (GEMM A input, dead after QKV GEMM)
    // [16,24) q8; [24,32) k8; [32,40) vT8 (fp8, from gemm_qkv epilogue)
    // [40,72) Opart bf16 (2 parts); [72,74) wT; [74,..) stats + ml
    short* xn    = (short*)ws;
    char*  q8    = (char*)(ws + 16 * MB);
    char*  k8    = (char*)(ws + 24 * MB);
    char*  vT8   = (char*)(ws + 32 * MB);
    short* Opart = (short*)(ws + 40 * MB);
    short* wT    = (short*)(ws + 72 * MB);
    float* stats = (float*)(ws + 74 * MB);
    float* ml    = (float*)(ws + 74 * MB + 65536);

    hipMemsetAsync(stats, 0, 256 * sizeof(float), stream);
    gn_wt_kernel<<<1280, 256, 0, stream>>>(x, stats, wq, wk, wv, wo, wT);
    gn_apply_kernel<<<8192, 256, 0, stream>>>(x, stats, gsc, gbs, xn);

    short* woT = wT + 786432;

    gemm_qkv_kernel<<<dim3(128, 12), 256, 0, stream>>>(xn, wT, bq, bk, bv, q8, k8, vT8);
    flash_kernel<<<256, 512, 0, stream>>>(q8, k8, vT8, Opart, ml);
    gemm_bt_kernel<<<dim3(128, 4), 256, 0, stream>>>(Opart, ml, woT, bo, out, x);
}

// Round 10
// 277.604 us; speedup vs baseline: 1.0674x; 1.0402x over previous
//
#include <hip/hip_runtime.h>
#include <hip/hip_bf16.h>
#include <stdint.h>

#define BATCH 4
#define SEQ   4096          // 64*64 spatial
#define CH    512
#define NGRP  32
#define GEPS  1e-6f

typedef short  short8  __attribute__((ext_vector_type(8)));
typedef float  floatx4 __attribute__((ext_vector_type(4)));
typedef long   longx2  __attribute__((ext_vector_type(2)));

static __device__ __forceinline__ short bf16b(float f) {
    __hip_bfloat16 h = __float2bfloat16(f);
    return __builtin_bit_cast(short, h);
}
static __device__ __forceinline__ float bf2f(short s) {
    unsigned u = ((unsigned)(unsigned short)s) << 16;
    return __builtin_bit_cast(float, u);
}
static __device__ __forceinline__ char fp8b(float f) {
    int pk = __builtin_amdgcn_cvt_pk_fp8_f32(f, f, 0, false);
    return (char)(pk & 0xff);
}

// async global->LDS, 16B per lane. LDS dest = wave-uniform base + lane*16.
static __device__ __forceinline__ void dma16(const void* g, void* l) {
    __builtin_amdgcn_global_load_lds(
        (const __attribute__((address_space(1))) unsigned int*)g,
        (__attribute__((address_space(3))) unsigned int*)l, 16, 0, 0);
}

// max-reduce across the 16 lanes of a DPP row, pure VALU
static __device__ __forceinline__ float rowmax16(float x) {
    int xi = __builtin_bit_cast(int, x);
    x = fmaxf(x, __builtin_bit_cast(float, __builtin_amdgcn_update_dpp(xi, xi, 0x128, 0xf, 0xf, true))); // row_ror:8
    xi = __builtin_bit_cast(int, x);
    x = fmaxf(x, __builtin_bit_cast(float, __builtin_amdgcn_update_dpp(xi, xi, 0x124, 0xf, 0xf, true))); // row_ror:4
    xi = __builtin_bit_cast(int, x);
    x = fmaxf(x, __builtin_bit_cast(float, __builtin_amdgcn_update_dpp(xi, xi, 0x122, 0xf, 0xf, true))); // row_ror:2
    xi = __builtin_bit_cast(int, x);
    x = fmaxf(x, __builtin_bit_cast(float, __builtin_amdgcn_update_dpp(xi, xi, 0x121, 0xf, 0xf, true))); // row_ror:1
    return x;
}

// ---------------- fused GroupNorm partial sums + weight transpose ----------------
__global__ __launch_bounds__(256) void gn_wt_kernel(const float* __restrict__ x,
                                                    float* __restrict__ statsraw,
                                                    const float* __restrict__ w0,
                                                    const float* __restrict__ w1,
                                                    const float* __restrict__ w2,
                                                    const float* __restrict__ w3,
                                                    short* __restrict__ wT) {
    __shared__ float a1[256], a2[256];
    __shared__ float trs[32][33];
    int blk = blockIdx.x;
    int t = threadIdx.x;
    if (blk < 256) {
        size_t row0 = (size_t)blk * 64;
        int qd = t & 127;
        int rh = t >> 7;
        const float* base = x + row0 * 512 + qd * 4;
        float s1 = 0.f, s2 = 0.f;
        #pragma unroll 4
        for (int i = 0; i < 32; ++i) {
            int r = rh + i * 2;
            float4 v = *reinterpret_cast<const float4*>(base + (size_t)r * 512);
            s1 += v.x + v.y + v.z + v.w;
            s2 += v.x * v.x + v.y * v.y + v.z * v.z + v.w * v.w;
        }
        a1[t] = s1; a2[t] = s2;
        __syncthreads();
        if (t < 32) {
            float u1 = 0.f, u2 = 0.f;
            #pragma unroll
            for (int e = 0; e < 4; ++e) {
                u1 += a1[t * 4 + e] + a1[128 + t * 4 + e];
                u2 += a2[t * 4 + e] + a2[128 + t * 4 + e];
            }
            int b = (int)(row0 >> 12);
            atomicAdd(&statsraw[(b * 32 + t) * 2],     u1);
            atomicAdd(&statsraw[(b * 32 + t) * 2 + 1], u2);
        }
    } else {
        int bz = (blk - 256) >> 8;
        int rem = (blk - 256) & 255;
        int n0 = (rem & 15) * 32, k0 = (rem >> 4) * 32;
        const float* w = (bz == 0) ? w0 : (bz == 1) ? w1 : (bz == 2) ? w2 : w3;
        short* out = wT + (size_t)bz * CH * CH;
        int tx = t & 31, ty = t >> 5;
        #pragma unroll
        for (int i = 0; i < 4; ++i) {
            int kk = ty + i * 8;
            trs[kk][tx] = w[(size_t)(k0 + kk) * CH + n0 + tx];
        }
        __syncthreads();
        #pragma unroll
        for (int i = 0; i < 4; ++i) {
            int nn = ty + i * 8;
            out[(size_t)(n0 + nn) * CH + k0 + tx] = bf16b(trs[tx][nn]);
        }
    }
}

// ---------------- GroupNorm apply ----------------
__global__ __launch_bounds__(256) void gn_apply_kernel(const float* __restrict__ x,
                                                       const float* __restrict__ statsraw,
                                                       const float* __restrict__ gsc,
                                                       const float* __restrict__ gbs,
                                                       short* __restrict__ xn) {
    int i4 = blockIdx.x * 256 + threadIdx.x;
    int base = i4 * 4;
    int b = base >> 21;
    int c = base & 511;
    int sidx = (b * 32 + (c >> 4)) * 2;
    float s1 = statsraw[sidx], s2 = statsraw[sidx + 1];
    float mean = s1 * (1.f / 65536.f);
    float var  = s2 * (1.f / 65536.f) - mean * mean;
    float rstd = rsqrtf(var + GEPS);
    float4 xv = reinterpret_cast<const float4*>(x)[i4];
    float4 sv = *reinterpret_cast<const float4*>(gsc + c);
    float4 bv = *reinterpret_cast<const float4*>(gbs + c);
    union { short s[4]; uint2 u; } p;
    p.s[0] = bf16b((xv.x - mean) * rstd * sv.x + bv.x);
    p.s[1] = bf16b((xv.y - mean) * rstd * sv.y + bv.y);
    p.s[2] = bf16b((xv.z - mean) * rstd * sv.z + bv.z);
    p.s[3] = bf16b((xv.w - mean) * rstd * sv.w + bv.w);
    reinterpret_cast<uint2*>(xn)[i4] = p.u;
}

// ---------------- fused QKV GEMM: fp8 epilogue (r8 version, unchanged) -------------
__global__ __launch_bounds__(256) void gemm_qkv_kernel(const short* __restrict__ A,
                                                       const short* __restrict__ wT,
                                                       const float* __restrict__ bq,
                                                       const float* __restrict__ bk,
                                                       const float* __restrict__ bv,
                                                       char* __restrict__ q8,
                                                       char* __restrict__ k8,
                                                       char* __restrict__ vT8) {
    __shared__ short As[128 * 64];
    __shared__ short Bs[128 * 64];
    __shared__ char  vls[128 * 144];   // fp8 store-staging, 18KB
    int m0 = blockIdx.x * 128;
    int nblk = blockIdx.y;                  // 0..11
    int which = nblk >> 2;                  // 0=q,1=k,2=v (block-uniform)
    int n0 = (nblk & 3) * 128;
    const short* BT = wT + (size_t)which * 512 * 512;
    const float* bias = (which == 0) ? bq : (which == 1) ? bk : bv;
    int t = threadIdx.x;
    int w = t >> 6, lane = t & 63;
    int wr = w >> 1, wc = w & 1;
    int l15 = lane & 15, l4 = lane >> 4;
    floatx4 acc[4][4];
    #pragma unroll
    for (int i = 0; i < 4; ++i)
        #pragma unroll
        for (int j = 0; j < 4; ++j) acc[i][j] = (floatx4){0.f, 0.f, 0.f, 0.f};

    for (int k0 = 0; k0 < 512; k0 += 64) {
        __syncthreads();
        #pragma unroll
        for (int i = 0; i < 4; ++i) {
            int c = i * 256 + t;
            int row = c >> 3, j = (c & 7) ^ (row & 7);
            dma16(&A[(size_t)(m0 + row) * 512 + k0 + j * 8], &As[(c & ~63) * 8]);
            dma16(&BT[(size_t)(n0 + row) * 512 + k0 + j * 8], &Bs[(c & ~63) * 8]);
        }
        __syncthreads();
        #pragma unroll
        for (int kk = 0; kk < 64; kk += 32) {
            short8 af[4], bf[4];
            #pragma unroll
            for (int i = 0; i < 4; ++i) {
                int row = wr * 64 + i * 16 + l15;
                int j = (kk >> 3) + l4;
                af[i] = *reinterpret_cast<const short8*>(&As[(row * 8 + (j ^ (l15 & 7))) * 8]);
            }
            #pragma unroll
            for (int j2 = 0; j2 < 4; ++j2) {
                int row = wc * 64 + j2 * 16 + l15;
                int j = (kk >> 3) + l4;
                bf[j2] = *reinterpret_cast<const short8*>(&Bs[(row * 8 + (j ^ (l15 & 7))) * 8]);
            }
            #pragma unroll
            for (int i = 0; i < 4; ++i)
                #pragma unroll
                for (int j2 = 0; j2 < 4; ++j2)
                    acc[i][j2] = __builtin_amdgcn_mfma_f32_16x16x32_bf16(af[i], bf[j2], acc[i][j2], 0, 0, 0);
        }
    }
    if (which == 0) {
        #pragma unroll
        for (int i = 0; i < 4; ++i)
            #pragma unroll
            for (int j = 0; j < 4; ++j)
                #pragma unroll
                for (int r = 0; r < 4; ++r) {
                    int rl = wr * 64 + i * 16 + l4 * 4 + r;
                    int cl = wc * 64 + j * 16 + l15;
                    vls[rl * 144 + cl] = fp8b(acc[i][j][r] + bias[n0 + cl]);
                }
        __syncthreads();
        #pragma unroll
        for (int p = 0; p < 4; ++p) {
            int slot = p * 256 + t;
            int c = slot >> 3, off = (slot & 7) * 16;
            uint4 v;
            __builtin_memcpy(&v, &vls[c * 144 + off], 16);
            *reinterpret_cast<uint4*>(&q8[(size_t)(m0 + c) * 512 + n0 + off]) = v;
        }
    } else if (which == 1) {
        #pragma unroll
        for (int i = 0; i < 4; ++i)
            #pragma unroll
            for (int j = 0; j < 4; ++j)
                #pragma unroll
                for (int r = 0; r < 4; ++r) {
                    int rl = wr * 64 + i * 16 + l4 * 4 + r;
                    int cl = wc * 64 + j * 16 + l15;
                    int sblk = rl >> 5, srow = rl & 15, hp = (rl >> 4) & 1;
                    int ch = (cl >> 3) ^ (srow & 7);
                    vls[sblk * 4096 + srow * 256 + ch * 16 + hp * 8 + (cl & 7)]
                        = fp8b(acc[i][j][r] + bias[n0 + cl]);
                }
        __syncthreads();
        int bb = m0 >> 12, sb0 = (m0 & 4095) >> 5;
        #pragma unroll
        for (int p = 0; p < 4; ++p) {
            int u = p * 256 + t;
            int sblk = u >> 8, srow = (u >> 4) & 15, ch = u & 15;
            uint4 v;
            __builtin_memcpy(&v, &vls[sblk * 4096 + srow * 256 + ((ch ^ (srow & 7)) * 16)], 16);
            char* dst = k8 + (size_t)bb * 2097152 + (size_t)(sb0 + sblk) * 16384
                      + srow * 1024 + n0 * 2 + ch * 16;
            *reinterpret_cast<uint4*>(dst) = v;
        }
    } else {
        __syncthreads();
        #pragma unroll
        for (int i = 0; i < 4; ++i)
            #pragma unroll
            for (int j = 0; j < 4; ++j)
                #pragma unroll
                for (int r = 0; r < 4; ++r) {
                    int rl = wr * 64 + i * 16 + l4 * 4 + r;     // local row (sequence)
                    int rp = (rl & ~31) | (((rl & 15) << 1) | ((rl >> 4) & 1));  // interleave
                    int cl = wc * 64 + j * 16 + l15;            // local col (d)
                    vls[cl * 144 + rp] = fp8b(acc[i][j][r] + bias[n0 + cl]);
                }
        __syncthreads();
        int b = m0 >> 12, l0 = m0 & 4095;
        #pragma unroll
        for (int p = 0; p < 4; ++p) {
            int slot = p * 256 + t;
            int c = slot >> 3, off = (slot & 7) * 16;   // off multiple of 16
            uint4 v;
            __builtin_memcpy(&v, &vls[c * 144 + off], 16);
            int dcol = n0 + c;
            int g = dcol >> 5, rr = dcol & 15, h = (dcol >> 4) & 1;
            int s = l0 + off;                    // interleaved s index, mult of 16
            int sb = s >> 5, mb = (s & 31) >> 3; // mb = 0 or 2
            char* dst = vT8 + (size_t)b * 2097152 + (size_t)sb * 16384
                      + (size_t)((((g * 16 + rr) * 4 + mb) * 16) + h * 8);
            unsigned long long lo = ((unsigned long long)v.y << 32) | v.x;
            unsigned long long hi = ((unsigned long long)v.w << 32) | v.z;
            *reinterpret_cast<unsigned long long*>(dst)      = lo;  // chunk mb
            *reinterpret_cast<unsigned long long*>(dst + 16) = hi;  // chunk mb+1
        }
    }
}

// ---------------- output GEMM with FUSED combine (merge coeffs hoisted) -------------
// ml max values are BASE-2; merge uses exp2f. e0/e1 are loop-invariant per row ->
// computed once before the K-loop (were recomputed 8x + 8x ml re-reads).
__global__ __launch_bounds__(256) void gemm_bt_kernel(const short* __restrict__ Opart,
                                                      const float* __restrict__ ml,
                                                      const short* __restrict__ BT,
                                                      const float* __restrict__ bias,
                                                      float* __restrict__ outf,
                                                      const float* __restrict__ resid) {
    __shared__ short As[128 * 64];
    __shared__ short Bs[128 * 64];
    int m0 = blockIdx.x * 128, n0 = blockIdx.y * 128;
    int t = threadIdx.x;
    int w = t >> 6, lane = t & 63;
    int wr = w >> 1, wc = w & 1;
    int l15 = lane & 15, l4 = lane >> 4;
    const size_t PART = (size_t)BATCH * SEQ;   // 16384 rows per part
    floatx4 acc[4][4];
    #pragma unroll
    for (int i = 0; i < 4; ++i)
        #pragma unroll
        for (int j = 0; j < 4; ++j) acc[i][j] = (floatx4){0.f, 0.f, 0.f, 0.f};

    float e0h[4], e1h[4];
    #pragma unroll
    for (int i = 0; i < 4; ++i) {
        int rl = (i * 256 + t) >> 3;
        size_t rowg = (size_t)(m0 + rl);
        float mA = ml[rowg * 2],          lA = ml[rowg * 2 + 1];
        float mB = ml[(PART + rowg) * 2], lB = ml[(PART + rowg) * 2 + 1];
        float mm = fmaxf(mA, mB);
        float e0 = exp2f(mA - mm), e1 = exp2f(mB - mm);
        float inv = 1.f / (e0 * lA + e1 * lB);
        e0h[i] = e0 * inv; e1h[i] = e1 * inv;
    }

    for (int k0 = 0; k0 < 512; k0 += 64) {
        __syncthreads();
        #pragma unroll
        for (int i = 0; i < 4; ++i) {
            int c = i * 256 + t;
            int rl = c >> 3, j = (c & 7) ^ (rl & 7);
            size_t rowg = (size_t)(m0 + rl);
            const short* s0 = Opart + rowg * 512 + k0 + j * 8;
            const short* s1 = s0 + PART * 512;
            uint4 a0 = *reinterpret_cast<const uint4*>(s0);
            uint4 a1 = *reinterpret_cast<const uint4*>(s1);
            union { uint4 u; short s[8]; } ua, ub, uo;
            ua.u = a0; ub.u = a1;
            #pragma unroll
            for (int e = 0; e < 8; ++e)
                uo.s[e] = bf16b(bf2f(ua.s[e]) * e0h[i] + bf2f(ub.s[e]) * e1h[i]);
            *reinterpret_cast<uint4*>(&As[c * 8]) = uo.u;    // ds_write_b128
            dma16(&BT[(size_t)(n0 + rl) * 512 + k0 + j * 8], &Bs[(c & ~63) * 8]);
        }
        __syncthreads();
        #pragma unroll
        for (int kk = 0; kk < 64; kk += 32) {
            short8 af[4], bf[4];
            #pragma unroll
            for (int i = 0; i < 4; ++i) {
                int row = wr * 64 + i * 16 + l15;
                int j = (kk >> 3) + l4;
                af[i] = *reinterpret_cast<const short8*>(&As[(row * 8 + (j ^ (l15 & 7))) * 8]);
            }
            #pragma unroll
            for (int j2 = 0; j2 < 4; ++j2) {
                int row = wc * 64 + j2 * 16 + l15;
                int j = (kk >> 3) + l4;
                bf[j2] = *reinterpret_cast<const short8*>(&Bs[(row * 8 + (j ^ (l15 & 7))) * 8]);
            }
            #pragma unroll
            for (int i = 0; i < 4; ++i)
                #pragma unroll
                for (int j2 = 0; j2 < 4; ++j2)
                    acc[i][j2] = __builtin_amdgcn_mfma_f32_16x16x32_bf16(af[i], bf[j2], acc[i][j2], 0, 0, 0);
        }
    }
    #pragma unroll
    for (int i = 0; i < 4; ++i)
        #pragma unroll
        for (int j = 0; j < 4; ++j)
            #pragma unroll
            for (int r = 0; r < 4; ++r) {
                int row = m0 + wr * 64 + i * 16 + l4 * 4 + r;
                int col = n0 + wc * 64 + j * 16 + l15;
                float vv = acc[i][j][r] + bias[col];
                outf[(size_t)row * 512 + col] = vv + resid[(size_t)row * 512 + col];
            }
}

// ---------------- flash attention: fp8, 64-col iterations (fixed-cost amortize) -----
// Round-7 8-wave body, but each iteration now processes TWO 32-s blocks:
// 32 iters x 1 barrier instead of 64. Mechanism: measured iter = 5089 cy vs
// ~3600 cy pipe demand -> ~1450 cy/iter fixed cost (barrier drain, QK->sm->PV
// phase transitions, rescale scan, loop control). Doubling work per iter halves
// the frequency of that fixed cost. LDS = K dbuf 64K | V dbuf 64K | P 8x1280
// = 141312 B (1 block/CU; 160K pool; 128K static LDS known-good on gfx950).
// Rescale scan now runs per 64 cols.
__global__ __launch_bounds__(512, 1) void flash_kernel(const char* __restrict__ q8,
                                                       const char* __restrict__ k8,
                                                       const char* __restrict__ v8,
                                                       short* __restrict__ Opart,
                                                       float* __restrict__ ml) {
    __shared__ __align__(16) char smem[141312];
    int bx = blockIdx.x;                 // 0..255
    int pb = bx & 7;                     // XCD-local (part,b)
    int part = pb >> 2, b = pb & 3;
    int q0 = (bx >> 3) * 128;            // 128 q rows per block
    int t = threadIdx.x, w = t >> 6, lane = t & 63;   // w = 0..7
    int l15 = lane & 15, l4 = lane >> 4;
    const float c2 = 0.06375873735f;     // (1/sqrt(512)) * log2(e)
    const float MARGIN = 7.2134752f;     // 5*log2(e); p <= 2^7.21 = 148 < 448

    // Q fp8 fragments: rows q0 + w*16 + l15, all 512 k (8 B per ks-step)
    long qf[16];
    {
        const char* qrow = q8 + ((size_t)b * SEQ + q0 + w * 16 + l15) * 512;
        #pragma unroll
        for (int ks = 0; ks < 16; ++ks)
            qf[ks] = *reinterpret_cast<const long*>(qrow + ks * 32 + l4 * 8);
    }

    floatx4 acc[32];
    #pragma unroll
    for (int i = 0; i < 32; ++i) acc[i] = (floatx4){0.f, 0.f, 0.f, 0.f};
    floatx4 lacc = (floatx4){0.f, 0.f, 0.f, 0.f};
    float mused[4] = {-1e30f, -1e30f, -1e30f, -1e30f};

    const long ones = 0x3838383838383838L;   // e4m3 1.0 x8

    const char* kbase = k8 + (size_t)b * SEQ * 512;
    const char* vbase = v8 + (size_t)b * 512 * SEQ;
    const int sb0 = part * 64;           // first 32-s block of this part

    const int ksw = l15 & 7;
    const int vsw = (l15 >> 1) & 3;
    // loop-invariant LDS read bases; per-iter offset = cur*32768, group2 +16384
    const char* kA_E = smem + ((l15 * 64 + (l4 ^ ksw)) << 4);
    const char* kA_O = smem + ((l15 * 64 + ((4 + l4) ^ ksw)) << 4);
    const char* vA   = smem + 65536 + ((l15 * 4 + (l4 ^ vsw)) << 4);
    char* Ps = smem + 131072 + w * 1280;   // 2 chunks of 640 per wave

    // precomputed per-thread DMA source byte-offsets (swizzle folded in).
    // 512 threads x 4 dma16 cover 2048 slots = two 16KB s-block tiles.
    int kSrc[4], vSrc[4];
    #pragma unroll
    for (int i = 0; i < 4; ++i) {
        int c = i * 512 + t;
        int tile = c >> 10, cw = c & 1023;
        kSrc[i] = tile * 16384 + (((cw & ~63) | ((cw & 63) ^ ((cw >> 6) & 7))) << 4);
        vSrc[i] = tile * 16384 + (((cw & ~3)  | ((cw & 3)  ^ ((cw >> 3) & 3))) << 4);
    }
    const int ldsD = (t & ~63) << 4;   // wave-uniform: w*1024

    // stage s-blocks sb, sb+1 into buffer `buf` (dest = linear slot*16)
    auto stage = [&](int sb, int buf) {
        const char* kt = kbase + (size_t)sb * 16384;
        const char* vt = vbase + (size_t)sb * 16384;
        char* Kd = smem + buf * 32768 + ldsD;
        char* Vd = smem + 65536 + buf * 32768 + ldsD;
        #pragma unroll
        for (int i = 0; i < 4; ++i) dma16(kt + kSrc[i], Kd + i * 8192);
        #pragma unroll
        for (int i = 0; i < 4; ++i) dma16(vt + vSrc[i], Vd + i * 8192);
    };

    stage(sb0, 0);
    __syncthreads();                                   // tiles 0,1 ready

    for (int it = 0; it < 32; ++it) {
        int cur = it & 1;
        int coff = cur << 15;
        if (it + 1 < 32) stage(sb0 + 2 * (it + 1), 1 - cur);

        // --- QK^T (fp8) over 64 s-cols: 4 C-tiles (2 col-pairs x 2 s-blocks)
        floatx4 s00 = (floatx4){0.f, 0.f, 0.f, 0.f};
        floatx4 s01 = (floatx4){0.f, 0.f, 0.f, 0.f};
        floatx4 s10 = (floatx4){0.f, 0.f, 0.f, 0.f};
        floatx4 s11 = (floatx4){0.f, 0.f, 0.f, 0.f};
        #pragma unroll
        for (int j = 0; j < 8; ++j) {
            longx2 kE0 = *reinterpret_cast<const longx2*>(kA_E + coff + j * 128);
            longx2 kO0 = *reinterpret_cast<const longx2*>(kA_O + coff + j * 128);
            longx2 kE1 = *reinterpret_cast<const longx2*>(kA_E + coff + 16384 + j * 128);
            longx2 kO1 = *reinterpret_cast<const longx2*>(kA_O + coff + 16384 + j * 128);
            s00 = __builtin_amdgcn_mfma_f32_16x16x32_fp8_fp8(qf[2 * j],     kE0[0], s00, 0, 0, 0);
            s01 = __builtin_amdgcn_mfma_f32_16x16x32_fp8_fp8(qf[2 * j],     kE0[1], s01, 0, 0, 0);
            s10 = __builtin_amdgcn_mfma_f32_16x16x32_fp8_fp8(qf[2 * j],     kE1[0], s10, 0, 0, 0);
            s11 = __builtin_amdgcn_mfma_f32_16x16x32_fp8_fp8(qf[2 * j],     kE1[1], s11, 0, 0, 0);
            s00 = __builtin_amdgcn_mfma_f32_16x16x32_fp8_fp8(qf[2 * j + 1], kO0[0], s00, 0, 0, 0);
            s01 = __builtin_amdgcn_mfma_f32_16x16x32_fp8_fp8(qf[2 * j + 1], kO0[1], s01, 0, 0, 0);
            s10 = __builtin_amdgcn_mfma_f32_16x16x32_fp8_fp8(qf[2 * j + 1], kO1[0], s10, 0, 0, 0);
            s11 = __builtin_amdgcn_mfma_f32_16x16x32_fp8_fp8(qf[2 * j + 1], kO1[1], s11, 0, 0, 0);
        }

        // --- online softmax over 64 cols, base-2, lazy rescale (1 scan / 64 cols)
        float v00[4], v01[4], v10[4], v11[4], nm4[4];
        bool need = false;
        #pragma unroll
        for (int r = 0; r < 4; ++r) {
            v00[r] = s00[r] * c2; v01[r] = s01[r] * c2;
            v10[r] = s10[r] * c2; v11[r] = s11[r] * c2;
            nm4[r] = rowmax16(fmaxf(fmaxf(v00[r], v01[r]), fmaxf(v10[r], v11[r])));
            need |= (nm4[r] > mused[r] + MARGIN);
        }
        if (__ballot(need)) {
            #pragma unroll
            for (int r = 0; r < 4; ++r) {
                float nm = fmaxf(mused[r], nm4[r]);
                float al = exp2f(mused[r] - nm);
                lacc[r] *= al;
                #pragma unroll
                for (int i = 0; i < 32; ++i) acc[i][r] *= al;
                mused[r] = nm;
            }
        }
        // P (fp8) writes: 2 chunks, interleaved col pairs (c, c+16)
        #pragma unroll
        for (int r = 0; r < 4; ++r) {
            int pk0 = __builtin_amdgcn_cvt_pk_fp8_f32(exp2f(v00[r] - mused[r]),
                                                      exp2f(v01[r] - mused[r]), 0, false);
            int pk1 = __builtin_amdgcn_cvt_pk_fp8_f32(exp2f(v10[r] - mused[r]),
                                                      exp2f(v11[r] - mused[r]), 0, false);
            *reinterpret_cast<short*>(Ps + (l4 * 4 + r) * 40 + l15 * 2)       = (short)pk0;
            *reinterpret_cast<short*>(Ps + 640 + (l4 * 4 + r) * 40 + l15 * 2) = (short)pk1;
        }

        // A-frag reads via memcpy (may-alias pun -> ordered AFTER the short stores)
        long pf0, pf1;
        __builtin_memcpy(&pf0, (const char*)__builtin_assume_aligned(Ps + l15 * 40 + l4 * 8, 8), 8);
        __builtin_memcpy(&pf1, (const char*)__builtin_assume_aligned(Ps + 640 + l15 * 40 + l4 * 8, 8), 8);
        lacc = __builtin_amdgcn_mfma_f32_16x16x32_fp8_fp8(pf0, ones, lacc, 0, 0, 0);
        lacc = __builtin_amdgcn_mfma_f32_16x16x32_fp8_fp8(pf1, ones, lacc, 0, 0, 0);
        // --- PV over both s-blocks (accumulate into same acc)
        #pragma unroll
        for (int g = 0; g < 16; ++g) {
            longx2 va = *reinterpret_cast<const longx2*>(vA + coff + g * 1024);
            acc[2 * g]     = __builtin_amdgcn_mfma_f32_16x16x32_fp8_fp8(pf0, va[0], acc[2 * g],     0, 0, 0);
            acc[2 * g + 1] = __builtin_amdgcn_mfma_f32_16x16x32_fp8_fp8(pf0, va[1], acc[2 * g + 1], 0, 0, 0);
        }
        #pragma unroll
        for (int g = 0; g < 16; ++g) {
            longx2 vb = *reinterpret_cast<const longx2*>(vA + coff + 16384 + g * 1024);
            acc[2 * g]     = __builtin_amdgcn_mfma_f32_16x16x32_fp8_fp8(pf1, vb[0], acc[2 * g],     0, 0, 0);
            acc[2 * g + 1] = __builtin_amdgcn_mfma_f32_16x16x32_fp8_fp8(pf1, vb[1], acc[2 * g + 1], 0, 0, 0);
        }

        __syncthreads();    // drains DMA(it+1) + all reads of buf[cur] done
    }

    short* obase = Opart + (((size_t)part * BATCH + b) * SEQ + q0 + w * 16) * 512;
    #pragma unroll
    for (int r = 0; r < 4; ++r) {
        #pragma unroll
        for (int tt = 0; tt < 32; ++tt)
            obase[(size_t)(l4 * 4 + r) * 512 + tt * 16 + l15] = bf16b(acc[tt][r]);
    }
    if (l15 == 0) {
        #pragma unroll
        for (int r = 0; r < 4; ++r) {
            size_t rowg = ((size_t)part * BATCH + b) * SEQ + q0 + w * 16 + l4 * 4 + r;
            ml[rowg * 2]     = mused[r];      // base-2 units
            ml[rowg * 2 + 1] = lacc[r];
        }
    }
}

extern "C" void kernel_launch(void* const* d_in, const int* in_sizes, int n_in,
                              void* d_out, int out_size, void* d_ws, size_t ws_size,
                              hipStream_t stream) {
    const float* x   = (const float*)d_in[0];
    const float* gsc = (const float*)d_in[1];
    const float* gbs = (const float*)d_in[2];
    const float* wq  = (const float*)d_in[3];
    const float* bq  = (const float*)d_in[4];
    const float* wk  = (const float*)d_in[5];
    const float* bk  = (const float*)d_in[6];
    const float* wv  = (const float*)d_in[7];
    const float* bv  = (const float*)d_in[8];
    const float* wo  = (const float*)d_in[9];
    const float* bo  = (const float*)d_in[10];
    float* out = (float*)d_out;

    char* ws = (char*)d_ws;
    const size_t MB = 1ull << 20;
    short* xn    = (short*)ws;
    char*  q8    = (char*)(ws + 16 * MB);
    char*  k8    = (char*)(ws + 24 * MB);
    char*  vT8   = (char*)(ws + 32 * MB);
    short* Opart = (short*)(ws + 40 * MB);
    short* wT    = (short*)(ws + 72 * MB);
    float* stats = (float*)(ws + 74 * MB);
    float* ml    = (float*)(ws + 74 * MB + 65536);

    hipMemsetAsync(stats, 0, 256 * sizeof(float), stream);
    gn_wt_kernel<<<1280, 256, 0, stream>>>(x, stats, wq, wk, wv, wo, wT);
    gn_apply_kernel<<<8192, 256, 0, stream>>>(x, stats, gsc, gbs, xn);

    short* woT = wT + 786432;

    gemm_qkv_kernel<<<dim3(128, 12), 256, 0, stream>>>(xn, wT, bq, bk, bv, q8, k8, vT8);
    flash_kernel<<<256, 512, 0, stream>>>(q8, k8, vT8, Opart, ml);
    gemm_bt_kernel<<<dim3(128, 4), 256, 0, stream>>>(Opart, ml, woT, bo, out, x);
}